// Round 3
// baseline (150774.231 us; speedup 1.0000x reference)
//
#include <hip/hip_runtime.h>
#include <hip/hip_bf16.h>
#include <math.h>

#define B 64
#define T 2048
#define D 128
#define H 256
#define G 1024          // 4*H gate rows

// per-q packed weight sizes (in uint = f16-pairs)
#define L0_UINTS 49152   // 192 kpairs * 256 cols
#define L1_UINTS 65536   // 256 kpairs * 256 cols
#define PQ_UINTS (L0_UINTS + L1_UINTS)   // 114688 per q

typedef _Float16 h2v __attribute__((ext_vector_type(2)));

#if defined(__has_builtin)
#if __has_builtin(__builtin_amdgcn_fdot2)
#define HAS_FDOT2 1
#endif
#endif

__device__ __forceinline__ float dot2(unsigned int w, unsigned int h, float acc) {
#ifdef HAS_FDOT2
    return __builtin_amdgcn_fdot2(__builtin_bit_cast(h2v, w), __builtin_bit_cast(h2v, h), acc, false);
#else
    h2v wv = __builtin_bit_cast(h2v, w);
    h2v hv = __builtin_bit_cast(h2v, h);
    acc = fmaf((float)wv.x, (float)hv.x, acc);
    return fmaf((float)wv.y, (float)hv.y, acc);
#endif
}

__device__ __forceinline__ unsigned short f2h(float f) {
    _Float16 h = (_Float16)f;
    return __builtin_bit_cast(unsigned short, h);
}
__device__ __forceinline__ float h2f(unsigned short u) {
    return (float)__builtin_bit_cast(_Float16, u);
}
__device__ __forceinline__ unsigned int packh2(float a, float b) {
    return (unsigned int)f2h(a) | ((unsigned int)f2h(b) << 16);
}
__device__ __forceinline__ float sigm(float x) { return 1.0f / (1.0f + __expf(-x)); }
__device__ __forceinline__ float ftanh(float x) {
    x = fminf(fmaxf(x, -15.0f), 15.0f);
    float e = __expf(2.0f * x);
    return (e - 1.0f) / (e + 1.0f);
}

// ---------------- prep ----------------
__global__ void k_zero(unsigned int* p, int n) {
    int i = blockIdx.x * blockDim.x + threadIdx.x;
    if (i < n) p[i] = 0u;
}

__global__ void k_bias_sum(const float* __restrict__ a, const float* __restrict__ b,
                           float* __restrict__ out, int n) {
    int i = blockIdx.x * blockDim.x + threadIdx.x;
    if (i < n) out[i] = a[i] + b[i];
}

// pack f32 weights -> f16 pairs, per-q column slices, k-major
// PW[q*PQ_UINTS + kp*256 + c] = (W(r, 2kp), W(r, 2kp+1)) where
//   c = gate*64 + u_loc, r = gate*256 + q*64 + u_loc
__global__ void k_pack_w(const float* __restrict__ Wih0, const float* __restrict__ Whh0,
                         const float* __restrict__ Wih1, const float* __restrict__ Whh1,
                         unsigned int* __restrict__ PW) {
    int idx = blockIdx.x * blockDim.x + threadIdx.x;
    if (idx >= 4 * PQ_UINTS) return;
    int q = idx / PQ_UINTS;
    int off = idx % PQ_UINTS;
    float v0, v1;
    if (off < L0_UINTS) {
        int kp = off >> 8, c = off & 255;
        int gate = c >> 6, u = c & 63;
        int r = gate * 256 + q * 64 + u;
        int k = kp * 2;
        if (k < 128) { v0 = Wih0[(size_t)r * 128 + k];       v1 = Wih0[(size_t)r * 128 + k + 1]; }
        else         { v0 = Whh0[(size_t)r * 256 + k - 128]; v1 = Whh0[(size_t)r * 256 + k - 127]; }
    } else {
        int o2 = off - L0_UINTS;
        int kp = o2 >> 8, c = o2 & 255;
        int gate = c >> 6, u = c & 63;
        int r = gate * 256 + q * 64 + u;
        int k = kp * 2;
        if (k < 256) { v0 = Wih1[(size_t)r * 256 + k];       v1 = Wih1[(size_t)r * 256 + k + 1]; }
        else         { v0 = Whh1[(size_t)r * 256 + k - 256]; v1 = Whh1[(size_t)r * 256 + k - 255]; }
    }
    PW[idx] = packh2(v0, v1);
}

// ---------------- split fused 2-layer LSTM ----------------
// grid = 256 WGs: q = bid>>6 (quarter), b = bid&63 (batch) -> 4 WGs of a batch
// land on the same XCD under round-robin dispatch.
// Per iteration t: layer0(t) and layer1(t-1) gates together, one exchange+sync.
__global__ __launch_bounds__(1024) void k_lstm_split(
    const float* __restrict__ x,        // B x T x D (f32)
    const unsigned int* __restrict__ PW,
    const float* __restrict__ bs0,      // G
    const float* __restrict__ bs1,      // G
    float* __restrict__ hx0,            // B x 2 x H
    float* __restrict__ hx1,            // B x 2 x H
    unsigned int* __restrict__ cnt,     // B
    unsigned short* __restrict__ seqo)  // B x T x H (f16)
{
    __shared__ float s_gacc[8][512];    // 16 KB
    __shared__ float s_g[512];
    __shared__ unsigned int s_k0p[192]; // [x pairs 0..63 | h0 pairs 64..191]
    __shared__ unsigned int s_k1p[256]; // [h0 pairs 0..127 | h1 pairs 128..255]

    const int q   = blockIdx.x >> 6;
    const int b   = blockIdx.x & 63;
    const int tid = threadIdx.x;
    const int kb  = tid >> 7;           // 8 k-blocks
    const int cg  = tid & 127;          // col-group: <64 -> L0 wave, >=64 -> L1 wave

    unsigned int* cnt_b = cnt + b;
    const unsigned int* Wq = PW + (size_t)q * PQ_UINTS;

    // owner bias registers (tid<128): 4 gates for this unit
    float bi0 = 0.f, bi1 = 0.f, bi2 = 0.f, bi3 = 0.f;
    if (tid < 64) {
        int u = q * 64 + tid;
        bi0 = bs0[u]; bi1 = bs0[256 + u]; bi2 = bs0[512 + u]; bi3 = bs0[768 + u];
    } else if (tid < 128) {
        int u = q * 64 + (tid - 64);
        bi0 = bs1[u]; bi1 = bs1[256 + u]; bi2 = bs1[512 + u]; bi3 = bs1[768 + u];
    }
    float c0 = 0.f, c1 = 0.f;

    // prologue staging: zeros for h0(-1), h1(-2); x(0)
    if (tid < 128) s_k0p[64 + tid] = 0u;
    if (tid >= 128 && tid < 384) s_k1p[tid - 128] = 0u;
    if (tid >= 256 && tid < 320) {
        int i = tid - 256;
        float2 v = ((const float2*)(x + (size_t)b * T * D))[i];
        s_k0p[i] = packh2(v.x, v.y);
    }

    for (int t = 0; ; ++t) {
        __syncthreads();                               // A: staging visible

        // ---- unified gemm: L0 waves (cols 0..255), L1 waves (cols 256..511) ----
        if (cg < 64) {
            if (t < T) {
                const unsigned int* Wp = Wq + (size_t)(kb * 24) * 256 + 4 * cg;
                float a0 = 0.f, a1 = 0.f, a2 = 0.f, a3 = 0.f;
                #pragma unroll
                for (int kp = 0; kp < 24; kp += 4) {
                    uint4 hp = *(const uint4*)&s_k0p[kb * 24 + kp];
                    uint4 w0 = *(const uint4*)(Wp);
                    uint4 w1 = *(const uint4*)(Wp + 256);
                    uint4 w2 = *(const uint4*)(Wp + 512);
                    uint4 w3 = *(const uint4*)(Wp + 768);
                    Wp += 1024;
                    a0 = dot2(w0.x, hp.x, a0); a1 = dot2(w0.y, hp.x, a1); a2 = dot2(w0.z, hp.x, a2); a3 = dot2(w0.w, hp.x, a3);
                    a0 = dot2(w1.x, hp.y, a0); a1 = dot2(w1.y, hp.y, a1); a2 = dot2(w1.z, hp.y, a2); a3 = dot2(w1.w, hp.y, a3);
                    a0 = dot2(w2.x, hp.z, a0); a1 = dot2(w2.y, hp.z, a1); a2 = dot2(w2.z, hp.z, a2); a3 = dot2(w2.w, hp.z, a3);
                    a0 = dot2(w3.x, hp.w, a0); a1 = dot2(w3.y, hp.w, a1); a2 = dot2(w3.z, hp.w, a2); a3 = dot2(w3.w, hp.w, a3);
                }
                *(float4*)&s_gacc[kb][4 * cg] = make_float4(a0, a1, a2, a3);
            }
        } else {
            const unsigned int* Wp = Wq + L0_UINTS + (size_t)(kb * 32) * 256 + 4 * (cg - 64);
            float a0 = 0.f, a1 = 0.f, a2 = 0.f, a3 = 0.f;
            #pragma unroll
            for (int kp = 0; kp < 32; kp += 4) {
                uint4 hp = *(const uint4*)&s_k1p[kb * 32 + kp];
                uint4 w0 = *(const uint4*)(Wp);
                uint4 w1 = *(const uint4*)(Wp + 256);
                uint4 w2 = *(const uint4*)(Wp + 512);
                uint4 w3 = *(const uint4*)(Wp + 768);
                Wp += 1024;
                a0 = dot2(w0.x, hp.x, a0); a1 = dot2(w0.y, hp.x, a1); a2 = dot2(w0.z, hp.x, a2); a3 = dot2(w0.w, hp.x, a3);
                a0 = dot2(w1.x, hp.y, a0); a1 = dot2(w1.y, hp.y, a1); a2 = dot2(w1.z, hp.y, a2); a3 = dot2(w1.w, hp.y, a3);
                a0 = dot2(w2.x, hp.z, a0); a1 = dot2(w2.y, hp.z, a1); a2 = dot2(w2.z, hp.z, a2); a3 = dot2(w2.w, hp.z, a3);
                a0 = dot2(w3.x, hp.w, a0); a1 = dot2(w3.y, hp.w, a1); a2 = dot2(w3.z, hp.w, a2); a3 = dot2(w3.w, hp.w, a3);
            }
            *(float4*)&s_gacc[kb][4 * cg] = make_float4(a0, a1, a2, a3);
        }
        __syncthreads();                               // B

        if (tid < 512) {
            float s = s_gacc[0][tid] + s_gacc[1][tid] + s_gacc[2][tid] + s_gacc[3][tid]
                    + s_gacc[4][tid] + s_gacc[5][tid] + s_gacc[6][tid] + s_gacc[7][tid];
            s_g[tid] = s;
        }
        __syncthreads();                               // C

        // ---- owners: nonlinearity + state update + publish ----
        if (tid < 64) {            // layer-0 unit q*64+tid, produces h0(t)
            if (t < T) {
                int u = tid;
                float gi = s_g[u] + bi0;
                float gf = s_g[64 + u] + bi1;
                float gg = s_g[128 + u] + bi2;
                float go = s_g[192 + u] + bi3;
                c0 = sigm(gf) * c0 + sigm(gi) * ftanh(gg);
                float h0v = sigm(go) * ftanh(c0);
                hx0[((size_t)b * 2 + (t & 1)) * H + q * 64 + u] = h0v;
            }
        } else if (tid < 128) {    // layer-1 unit, produces h1(t-1)
            int u = tid - 64;
            float h1v = 0.0f;
            if (t >= 1) {
                float gi = s_g[256 + u] + bi0;
                float gf = s_g[320 + u] + bi1;
                float gg = s_g[384 + u] + bi2;
                float go = s_g[448 + u] + bi3;
                c1 = sigm(gf) * c1 + sigm(gi) * ftanh(gg);
                h1v = sigm(go) * ftanh(c1);
                seqo[((size_t)b * T + (t - 1)) * H + q * 64 + u] = f2h(h1v);
            }
            if (t < T) hx1[((size_t)b * 2 + (t & 1)) * H + q * 64 + u] = h1v;
        }

        if (t == T) break;                             // uniform exit

        __syncthreads();                               // D1: owner stores drained (vmcnt at barrier)

        if (tid == 0) {
            __hip_atomic_fetch_add(cnt_b, 1u, __ATOMIC_RELEASE, __HIP_MEMORY_SCOPE_AGENT);
            while (__hip_atomic_load(cnt_b, __ATOMIC_ACQUIRE, __HIP_MEMORY_SCOPE_AGENT) < 4u * (unsigned)(t + 1))
                __builtin_amdgcn_s_sleep(1);
        }
        __syncthreads();                               // D2
        __threadfence();                               // invalidate L1 for fresh hx reads

        // ---- read full h0(t), h1(t-1); stage f16-packed LDS; prefetch x(t+1) ----
        {
            const int buf = t & 1;
            if (tid < 128) {
                float2 v = ((const float2*)(hx0 + ((size_t)b * 2 + buf) * H))[tid];
                unsigned int u = packh2(v.x, v.y);
                s_k0p[64 + tid] = u;
                s_k1p[tid] = u;
            } else if (tid < 256) {
                int i = tid - 128;
                float2 v = ((const float2*)(hx1 + ((size_t)b * 2 + buf) * H))[i];
                s_k1p[128 + i] = packh2(v.x, v.y);
            } else if (tid < 320 && (t + 1) < T) {
                int i = tid - 256;
                float2 v = ((const float2*)(x + ((size_t)b * T + (t + 1)) * D))[i];
                s_k0p[i] = packh2(v.x, v.y);
            }
        }
    }
}

// ---------------- attention ----------------
__global__ __launch_bounds__(256) void k_a2(const unsigned short* __restrict__ lstm_out,
                                            const float* __restrict__ W2,
                                            float* __restrict__ a2out)
{
    __shared__ float s_hT[H];
    int b = blockIdx.x;
    int k = threadIdx.x;
    s_hT[k] = h2f(lstm_out[((size_t)b * T + (T - 1)) * H + k]);
    __syncthreads();
    float acc = 0.f;
    #pragma unroll 4
    for (int h = 0; h < H; ++h) acc += s_hT[h] * W2[h * H + k];
    a2out[b * H + k] = acc;
}

__global__ __launch_bounds__(256) void k_scores(const unsigned short* __restrict__ lstm_out,
                                                const float* __restrict__ W1,
                                                const float* __restrict__ a2,
                                                const float* __restrict__ attn_w,
                                                float* __restrict__ scores)
{
    const int RPB = 32;
    __shared__ float s_rows[RPB][H];   // 32 KB
    __shared__ float s_part[RPB][4];
    int b   = blockIdx.y;
    int t0  = blockIdx.x * RPB;
    int tid = threadIdx.x;

    const unsigned short* lp = lstm_out + ((size_t)b * T + t0) * H;
    for (int i = tid; i < RPB * H / 4; i += 256) {
        ushort4 v = ((const ushort4*)lp)[i];
        int e = i * 4, r = e >> 8, h0 = e & 255;
        *(float4*)&s_rows[r][h0] = make_float4(h2f(v.x), h2f(v.y), h2f(v.z), h2f(v.w));
    }
    __syncthreads();

    int c = tid;
    float acc[RPB];
    #pragma unroll
    for (int r = 0; r < RPB; ++r) acc[r] = 0.f;
    for (int h = 0; h < H; ++h) {
        float w = W1[h * H + c];
        #pragma unroll
        for (int r = 0; r < RPB; ++r) acc[r] += s_rows[r][h] * w;
    }
    float a2v = a2[b * H + c];
    float wc  = attn_w[c];
    int lane = tid & 63, wv = tid >> 6;
    #pragma unroll
    for (int r = 0; r < RPB; ++r) {
        float v = ftanh(acc[r] + a2v) * wc;
        for (int off = 32; off; off >>= 1) v += __shfl_down(v, off);
        if (lane == 0) s_part[r][wv] = v;
    }
    __syncthreads();
    if (tid < RPB) {
        scores[(size_t)b * T + t0 + tid] =
            s_part[tid][0] + s_part[tid][1] + s_part[tid][2] + s_part[tid][3];
    }
}

__global__ __launch_bounds__(256) void k_finish(const unsigned short* __restrict__ lstm_out,
                                                const float* __restrict__ scores,
                                                const float* __restrict__ gamma,
                                                const float* __restrict__ beta,
                                                float* __restrict__ out)
{
    __shared__ float s_p[T];
    __shared__ float s_red[4];
    const int b = blockIdx.x;
    const int tid = threadIdx.x;
    const int lane = tid & 63, wv = tid >> 6;

    const float* sc = scores + (size_t)b * T;
    float m = -1e30f;
    for (int t = tid; t < T; t += 256) m = fmaxf(m, sc[t]);
    for (int off = 32; off; off >>= 1) m = fmaxf(m, __shfl_down(m, off));
    if (lane == 0) s_red[wv] = m;
    __syncthreads();
    m = fmaxf(fmaxf(s_red[0], s_red[1]), fmaxf(s_red[2], s_red[3]));
    __syncthreads();

    float z = 0.f;
    for (int t = tid; t < T; t += 256) { float e = __expf(sc[t] - m); s_p[t] = e; z += e; }
    for (int off = 32; off; off >>= 1) z += __shfl_down(z, off);
    if (lane == 0) s_red[wv] = z;
    __syncthreads();
    z = s_red[0] + s_red[1] + s_red[2] + s_red[3];
    float rz = 1.0f / z;
    __syncthreads();

    const unsigned short* lp = lstm_out + (size_t)b * T * H + tid;
    float ctx = 0.f;
    for (int t = 0; t < T; ++t) ctx += s_p[t] * h2f(lp[(size_t)t * H]);
    ctx *= rz;

    float s1 = ctx;
    for (int off = 32; off; off >>= 1) s1 += __shfl_down(s1, off);
    if (lane == 0) s_red[wv] = s1;
    __syncthreads();
    float mu = (s_red[0] + s_red[1] + s_red[2] + s_red[3]) * (1.0f / H);
    __syncthreads();
    float dv = ctx - mu;
    float s2 = dv * dv;
    for (int off = 32; off; off >>= 1) s2 += __shfl_down(s2, off);
    if (lane == 0) s_red[wv] = s2;
    __syncthreads();
    float var = (s_red[0] + s_red[1] + s_red[2] + s_red[3]) * (1.0f / H);
    out[b * H + tid] = dv * rsqrtf(var + 1e-5f) * gamma[tid] + beta[tid];
}

// ---------------- host ----------------
extern "C" void kernel_launch(void* const* d_in, const int* in_sizes, int n_in,
                              void* d_out, int out_size, void* d_ws, size_t ws_size,
                              hipStream_t stream) {
    const float* x     = (const float*)d_in[0];
    const float* Wih0  = (const float*)d_in[1];
    const float* Whh0  = (const float*)d_in[2];
    const float* bih0  = (const float*)d_in[3];
    const float* bhh0  = (const float*)d_in[4];
    const float* Wih1  = (const float*)d_in[5];
    const float* Whh1  = (const float*)d_in[6];
    const float* bih1  = (const float*)d_in[7];
    const float* bhh1  = (const float*)d_in[8];
    const float* aW1   = (const float*)d_in[9];
    const float* aW2   = (const float*)d_in[10];
    const float* aw    = (const float*)d_in[11];
    const float* gamma = (const float*)d_in[12];
    const float* beta  = (const float*)d_in[13];
    float* out = (float*)d_out;

    // ---- workspace layout (bytes), total ~66.3 MB ----
    char* base = (char*)d_ws;
    unsigned int* PW   = (unsigned int*)(base);                    // 1,835,008 B
    float* bsum0       = (float*)(base + 1835008);                 // 4096 B
    float* bsum1       = (float*)(base + 1839104);                 // 4096 B
    unsigned int* cnt  = (unsigned int*)(base + 1843200);          // 256 B
    float* hx0         = (float*)(base + 1843456);                 // 131,072 B
    float* hx1         = (float*)(base + 1974528);                 // 131,072 B
    // attention buffers overlap the hx region (used only after the LSTM kernel)
    float* a2buf       = (float*)(base + 1843456);                 // 65,536 B
    float* scoresb     = (float*)(base + 1908992);                 // 524,288 B
    unsigned short* lstm2 = (unsigned short*)(base + 2433280);     // 67,108,864 B (B*T*H f16)
    // NOTE: a2buf/scoresb alias hx0/hx1 — hx is dead once k_lstm_split finishes.

    k_zero<<<1, 64, 0, stream>>>(cnt, B);
    k_pack_w<<<(4 * PQ_UINTS) / 256, 256, 0, stream>>>(Wih0, Whh0, Wih1, Whh1, PW);
    k_bias_sum<<<(G + 255) / 256, 256, 0, stream>>>(bih0, bhh0, bsum0, G);
    k_bias_sum<<<(G + 255) / 256, 256, 0, stream>>>(bih1, bhh1, bsum1, G);

    k_lstm_split<<<256, 1024, 0, stream>>>(x, PW, bsum0, bsum1, hx0, hx1, cnt, lstm2);

    k_a2<<<B, H, 0, stream>>>(lstm2, aW2, a2buf);
    k_scores<<<dim3(T / 32, B), 256, 0, stream>>>(lstm2, aW1, a2buf, aw, scoresb);
    k_finish<<<B, 256, 0, stream>>>(lstm2, scoresb, gamma, beta, out);
}

// Round 4
// 19197.704 us; speedup vs baseline: 7.8538x; 7.8538x over previous
//
#include <hip/hip_runtime.h>
#include <hip/hip_bf16.h>
#include <math.h>

#define B 64
#define T 2048
#define D 128
#define H 256
#define G 1024          // 4*H gate rows

// per-q packed weight sizes (in uint = f16-pairs)
#define L0_UINTS 49152   // 192 kpairs * 256 cols
#define L1_UINTS 65536   // 256 kpairs * 256 cols
#define PQ_UINTS (L0_UINTS + L1_UINTS)   // 114688 per q

#define CNT_STRIDE 64    // uints per batch counter (256 B line padding)

typedef _Float16 h2v __attribute__((ext_vector_type(2)));

#if defined(__has_builtin)
#if __has_builtin(__builtin_amdgcn_fdot2)
#define HAS_FDOT2 1
#endif
#endif

__device__ __forceinline__ float dot2(unsigned int w, unsigned int h, float acc) {
#ifdef HAS_FDOT2
    return __builtin_amdgcn_fdot2(__builtin_bit_cast(h2v, w), __builtin_bit_cast(h2v, h), acc, false);
#else
    h2v wv = __builtin_bit_cast(h2v, w);
    h2v hv = __builtin_bit_cast(h2v, h);
    acc = fmaf((float)wv.x, (float)hv.x, acc);
    return fmaf((float)wv.y, (float)hv.y, acc);
#endif
}

__device__ __forceinline__ unsigned short f2h(float f) {
    _Float16 h = (_Float16)f;
    return __builtin_bit_cast(unsigned short, h);
}
__device__ __forceinline__ float h2f(unsigned short u) {
    return (float)__builtin_bit_cast(_Float16, u);
}
__device__ __forceinline__ unsigned int packh2(float a, float b) {
    return (unsigned int)f2h(a) | ((unsigned int)f2h(b) << 16);
}
__device__ __forceinline__ float sigm(float x) { return 1.0f / (1.0f + __expf(-x)); }
__device__ __forceinline__ float ftanh(float x) {
    x = fminf(fmaxf(x, -15.0f), 15.0f);
    float e = __expf(2.0f * x);
    return (e - 1.0f) / (e + 1.0f);
}

// ---------------- prep ----------------
__global__ void k_zero(unsigned int* p, int n) {
    int i = blockIdx.x * blockDim.x + threadIdx.x;
    if (i < n) p[i] = 0u;
}

__global__ void k_bias_sum(const float* __restrict__ a, const float* __restrict__ b,
                           float* __restrict__ out, int n) {
    int i = blockIdx.x * blockDim.x + threadIdx.x;
    if (i < n) out[i] = a[i] + b[i];
}

// pack f32 weights -> f16 pairs, per-q column slices, k-major
__global__ void k_pack_w(const float* __restrict__ Wih0, const float* __restrict__ Whh0,
                         const float* __restrict__ Wih1, const float* __restrict__ Whh1,
                         unsigned int* __restrict__ PW) {
    int idx = blockIdx.x * blockDim.x + threadIdx.x;
    if (idx >= 4 * PQ_UINTS) return;
    int q = idx / PQ_UINTS;
    int off = idx % PQ_UINTS;
    float v0, v1;
    if (off < L0_UINTS) {
        int kp = off >> 8, c = off & 255;
        int gate = c >> 6, u = c & 63;
        int r = gate * 256 + q * 64 + u;
        int k = kp * 2;
        if (k < 128) { v0 = Wih0[(size_t)r * 128 + k];       v1 = Wih0[(size_t)r * 128 + k + 1]; }
        else         { v0 = Whh0[(size_t)r * 256 + k - 128]; v1 = Whh0[(size_t)r * 256 + k - 127]; }
    } else {
        int o2 = off - L0_UINTS;
        int kp = o2 >> 8, c = o2 & 255;
        int gate = c >> 6, u = c & 63;
        int r = gate * 256 + q * 64 + u;
        int k = kp * 2;
        if (k < 256) { v0 = Wih1[(size_t)r * 256 + k];       v1 = Wih1[(size_t)r * 256 + k + 1]; }
        else         { v0 = Whh1[(size_t)r * 256 + k - 256]; v1 = Whh1[(size_t)r * 256 + k - 255]; }
    }
    PW[idx] = packh2(v0, v1);
}

// ---------------- split fused 2-layer LSTM ----------------
// grid = 256 WGs: q = bid>>6, b = bid&63. Per iteration t: layer0(t) and
// layer1(t-1) gates together; ONE fence-free exchange+sync per step.
// Exchange: packed f16-pair uints through L3 via RELAXED agent-scope atomics
// (no acquire/release/threadfence -> no L1/L2 invalidation -> weights stay
// L2-resident). Store completion is guaranteed by the vmcnt(0) the compiler
// emits at the __syncthreads() preceding the flag publish.
__global__ __launch_bounds__(1024) void k_lstm_split(
    const float* __restrict__ x,        // B x T x D (f32)
    const unsigned int* __restrict__ PW,
    const float* __restrict__ bs0,      // G
    const float* __restrict__ bs1,      // G
    unsigned int* __restrict__ hxp0,    // B x 2 x 128 (f16-pair packed h0)
    unsigned int* __restrict__ hxp1,    // B x 2 x 128 (f16-pair packed h1)
    unsigned int* __restrict__ cnt,     // B x CNT_STRIDE
    unsigned short* __restrict__ seqo)  // B x T x H (f16)
{
    __shared__ float s_gacc[8][512];    // 16 KB
    __shared__ float s_g[512];
    __shared__ unsigned int s_k0p[192]; // [x pairs 0..63 | h0 pairs 64..191]
    __shared__ unsigned int s_k1p[256]; // [h0 pairs 0..127 | h1 pairs 128..255]

    const int q   = blockIdx.x >> 6;
    const int b   = blockIdx.x & 63;
    const int tid = threadIdx.x;
    const int kb  = tid >> 7;           // 8 k-blocks
    const int cg  = tid & 127;          // col-group: <64 -> L0, >=64 -> L1

    unsigned int* cnt_b = cnt + (size_t)b * CNT_STRIDE;
    const unsigned int* Wq = PW + (size_t)q * PQ_UINTS;

    float bi0 = 0.f, bi1 = 0.f, bi2 = 0.f, bi3 = 0.f;
    if (tid < 64) {
        int u = q * 64 + tid;
        bi0 = bs0[u]; bi1 = bs0[256 + u]; bi2 = bs0[512 + u]; bi3 = bs0[768 + u];
    } else if (tid < 128) {
        int u = q * 64 + (tid - 64);
        bi0 = bs1[u]; bi1 = bs1[256 + u]; bi2 = bs1[512 + u]; bi3 = bs1[768 + u];
    }
    float c0 = 0.f, c1 = 0.f;

    // prologue staging: zeros for h0(-1), h1(-2); x(0)
    if (tid < 128) s_k0p[64 + tid] = 0u;
    if (tid >= 128 && tid < 384) s_k1p[tid - 128] = 0u;
    if (tid >= 256 && tid < 320) {
        int i = tid - 256;
        float2 v = ((const float2*)(x + (size_t)b * T * D))[i];
        s_k0p[i] = packh2(v.x, v.y);
    }

    for (int t = 0; ; ++t) {
        __syncthreads();                               // A: staging visible

        // ---- unified gemm: L0 waves (cols 0..255), L1 waves (cols 256..511) ----
        if (cg < 64) {
            if (t < T) {
                const unsigned int* Wp = Wq + (size_t)(kb * 24) * 256 + 4 * cg;
                float a0 = 0.f, a1 = 0.f, a2 = 0.f, a3 = 0.f;
                #pragma unroll
                for (int kp = 0; kp < 24; kp += 4) {
                    uint4 hp = *(const uint4*)&s_k0p[kb * 24 + kp];
                    uint4 w0 = *(const uint4*)(Wp);
                    uint4 w1 = *(const uint4*)(Wp + 256);
                    uint4 w2 = *(const uint4*)(Wp + 512);
                    uint4 w3 = *(const uint4*)(Wp + 768);
                    Wp += 1024;
                    a0 = dot2(w0.x, hp.x, a0); a1 = dot2(w0.y, hp.x, a1); a2 = dot2(w0.z, hp.x, a2); a3 = dot2(w0.w, hp.x, a3);
                    a0 = dot2(w1.x, hp.y, a0); a1 = dot2(w1.y, hp.y, a1); a2 = dot2(w1.z, hp.y, a2); a3 = dot2(w1.w, hp.y, a3);
                    a0 = dot2(w2.x, hp.z, a0); a1 = dot2(w2.y, hp.z, a1); a2 = dot2(w2.z, hp.z, a2); a3 = dot2(w2.w, hp.z, a3);
                    a0 = dot2(w3.x, hp.w, a0); a1 = dot2(w3.y, hp.w, a1); a2 = dot2(w3.z, hp.w, a2); a3 = dot2(w3.w, hp.w, a3);
                }
                *(float4*)&s_gacc[kb][4 * cg] = make_float4(a0, a1, a2, a3);
            }
        } else {
            const unsigned int* Wp = Wq + L0_UINTS + (size_t)(kb * 32) * 256 + 4 * (cg - 64);
            float a0 = 0.f, a1 = 0.f, a2 = 0.f, a3 = 0.f;
            #pragma unroll
            for (int kp = 0; kp < 32; kp += 4) {
                uint4 hp = *(const uint4*)&s_k1p[kb * 32 + kp];
                uint4 w0 = *(const uint4*)(Wp);
                uint4 w1 = *(const uint4*)(Wp + 256);
                uint4 w2 = *(const uint4*)(Wp + 512);
                uint4 w3 = *(const uint4*)(Wp + 768);
                Wp += 1024;
                a0 = dot2(w0.x, hp.x, a0); a1 = dot2(w0.y, hp.x, a1); a2 = dot2(w0.z, hp.x, a2); a3 = dot2(w0.w, hp.x, a3);
                a0 = dot2(w1.x, hp.y, a0); a1 = dot2(w1.y, hp.y, a1); a2 = dot2(w1.z, hp.y, a2); a3 = dot2(w1.w, hp.y, a3);
                a0 = dot2(w2.x, hp.z, a0); a1 = dot2(w2.y, hp.z, a1); a2 = dot2(w2.z, hp.z, a2); a3 = dot2(w2.w, hp.z, a3);
                a0 = dot2(w3.x, hp.w, a0); a1 = dot2(w3.y, hp.w, a1); a2 = dot2(w3.z, hp.w, a2); a3 = dot2(w3.w, hp.w, a3);
            }
            *(float4*)&s_gacc[kb][4 * cg] = make_float4(a0, a1, a2, a3);
        }
        __syncthreads();                               // B

        if (tid < 512) {
            float s = s_gacc[0][tid] + s_gacc[1][tid] + s_gacc[2][tid] + s_gacc[3][tid]
                    + s_gacc[4][tid] + s_gacc[5][tid] + s_gacc[6][tid] + s_gacc[7][tid];
            s_g[tid] = s;
        }
        __syncthreads();                               // C

        // ---- owners: nonlinearity + state update + publish (packed, relaxed) ----
        if (tid < 64) {            // layer-0 unit q*64+tid -> h0(t)
            if (t < T) {
                int u = tid;
                float gi = s_g[u] + bi0;
                float gf = s_g[64 + u] + bi1;
                float gg = s_g[128 + u] + bi2;
                float go = s_g[192 + u] + bi3;
                c0 = sigm(gf) * c0 + sigm(gi) * ftanh(gg);
                float h0v = sigm(go) * ftanh(c0);
                float other = __shfl_xor(h0v, 1);
                if ((u & 1) == 0) {
                    __hip_atomic_store(hxp0 + ((size_t)b * 2 + (t & 1)) * 128 + q * 32 + (u >> 1),
                                       packh2(h0v, other), __ATOMIC_RELAXED, __HIP_MEMORY_SCOPE_AGENT);
                }
            }
        } else if (tid < 128) {    // layer-1 unit -> h1(t-1)
            int u = tid - 64;
            float h1v = 0.0f;
            if (t >= 1) {
                float gi = s_g[256 + u] + bi0;
                float gf = s_g[320 + u] + bi1;
                float gg = s_g[384 + u] + bi2;
                float go = s_g[448 + u] + bi3;
                c1 = sigm(gf) * c1 + sigm(gi) * ftanh(gg);
                h1v = sigm(go) * ftanh(c1);
                seqo[((size_t)b * T + (t - 1)) * H + q * 64 + u] = f2h(h1v);
            }
            if (t < T) {
                float other = __shfl_xor(h1v, 1);
                if ((u & 1) == 0) {
                    __hip_atomic_store(hxp1 + ((size_t)b * 2 + (t & 1)) * 128 + q * 32 + (u >> 1),
                                       packh2(h1v, other), __ATOMIC_RELAXED, __HIP_MEMORY_SCOPE_AGENT);
                }
            }
        }

        if (t == T) break;                             // uniform exit

        __syncthreads();                               // D1: all waves' stores drained (vmcnt0 at barrier)

        if (tid == 0) {
            __hip_atomic_fetch_add(cnt_b, 1u, __ATOMIC_RELAXED, __HIP_MEMORY_SCOPE_AGENT);
            while (__hip_atomic_fetch_add(cnt_b, 0u, __ATOMIC_RELAXED, __HIP_MEMORY_SCOPE_AGENT)
                   < 4u * (unsigned)(t + 1))
                __builtin_amdgcn_s_sleep(1);
        }
        __syncthreads();                               // D2

        // ---- read packed h0(t), h1(t-1) from L3; prefetch x(t+1) ----
        {
            const int buf = t & 1;
            if (tid < 128) {
                unsigned int u0 = __hip_atomic_load(hxp0 + ((size_t)b * 2 + buf) * 128 + tid,
                                                    __ATOMIC_RELAXED, __HIP_MEMORY_SCOPE_AGENT);
                s_k0p[64 + tid] = u0;
                s_k1p[tid]      = u0;
            } else if (tid < 256) {
                int i = tid - 128;
                s_k1p[128 + i] = __hip_atomic_load(hxp1 + ((size_t)b * 2 + buf) * 128 + i,
                                                   __ATOMIC_RELAXED, __HIP_MEMORY_SCOPE_AGENT);
            } else if (tid < 320 && (t + 1) < T) {
                int i = tid - 256;
                float2 v = ((const float2*)(x + ((size_t)b * T + (t + 1)) * D))[i];
                s_k0p[i] = packh2(v.x, v.y);
            }
        }
    }
}

// ---------------- attention ----------------
__global__ __launch_bounds__(256) void k_a2(const unsigned short* __restrict__ lstm_out,
                                            const float* __restrict__ W2,
                                            float* __restrict__ a2out)
{
    __shared__ float s_hT[H];
    int b = blockIdx.x;
    int k = threadIdx.x;
    s_hT[k] = h2f(lstm_out[((size_t)b * T + (T - 1)) * H + k]);
    __syncthreads();
    float acc = 0.f;
    #pragma unroll 4
    for (int h = 0; h < H; ++h) acc += s_hT[h] * W2[h * H + k];
    a2out[b * H + k] = acc;
}

__global__ __launch_bounds__(256) void k_scores(const unsigned short* __restrict__ lstm_out,
                                                const float* __restrict__ W1,
                                                const float* __restrict__ a2,
                                                const float* __restrict__ attn_w,
                                                float* __restrict__ scores)
{
    const int RPB = 32;
    __shared__ float s_rows[RPB][H];   // 32 KB
    __shared__ float s_part[RPB][4];
    int b   = blockIdx.y;
    int t0  = blockIdx.x * RPB;
    int tid = threadIdx.x;

    const unsigned short* lp = lstm_out + ((size_t)b * T + t0) * H;
    for (int i = tid; i < RPB * H / 4; i += 256) {
        ushort4 v = ((const ushort4*)lp)[i];
        int e = i * 4, r = e >> 8, h0 = e & 255;
        *(float4*)&s_rows[r][h0] = make_float4(h2f(v.x), h2f(v.y), h2f(v.z), h2f(v.w));
    }
    __syncthreads();

    int c = tid;
    float acc[RPB];
    #pragma unroll
    for (int r = 0; r < RPB; ++r) acc[r] = 0.f;
    for (int h = 0; h < H; ++h) {
        float w = W1[h * H + c];
        #pragma unroll
        for (int r = 0; r < RPB; ++r) acc[r] += s_rows[r][h] * w;
    }
    float a2v = a2[b * H + c];
    float wc  = attn_w[c];
    int lane = tid & 63, wv = tid >> 6;
    #pragma unroll
    for (int r = 0; r < RPB; ++r) {
        float v = ftanh(acc[r] + a2v) * wc;
        for (int off = 32; off; off >>= 1) v += __shfl_down(v, off);
        if (lane == 0) s_part[r][wv] = v;
    }
    __syncthreads();
    if (tid < RPB) {
        scores[(size_t)b * T + t0 + tid] =
            s_part[tid][0] + s_part[tid][1] + s_part[tid][2] + s_part[tid][3];
    }
}

__global__ __launch_bounds__(256) void k_finish(const unsigned short* __restrict__ lstm_out,
                                                const float* __restrict__ scores,
                                                const float* __restrict__ gamma,
                                                const float* __restrict__ beta,
                                                float* __restrict__ out)
{
    __shared__ float s_p[T];
    __shared__ float s_red[4];
    const int b = blockIdx.x;
    const int tid = threadIdx.x;
    const int lane = tid & 63, wv = tid >> 6;

    const float* sc = scores + (size_t)b * T;
    float m = -1e30f;
    for (int t = tid; t < T; t += 256) m = fmaxf(m, sc[t]);
    for (int off = 32; off; off >>= 1) m = fmaxf(m, __shfl_down(m, off));
    if (lane == 0) s_red[wv] = m;
    __syncthreads();
    m = fmaxf(fmaxf(s_red[0], s_red[1]), fmaxf(s_red[2], s_red[3]));
    __syncthreads();

    float z = 0.f;
    for (int t = tid; t < T; t += 256) { float e = __expf(sc[t] - m); s_p[t] = e; z += e; }
    for (int off = 32; off; off >>= 1) z += __shfl_down(z, off);
    if (lane == 0) s_red[wv] = z;
    __syncthreads();
    z = s_red[0] + s_red[1] + s_red[2] + s_red[3];
    float rz = 1.0f / z;
    __syncthreads();

    const unsigned short* lp = lstm_out + (size_t)b * T * H + tid;
    float ctx = 0.f;
    for (int t = 0; t < T; ++t) ctx += s_p[t] * h2f(lp[(size_t)t * H]);
    ctx *= rz;

    float s1 = ctx;
    for (int off = 32; off; off >>= 1) s1 += __shfl_down(s1, off);
    if (lane == 0) s_red[wv] = s1;
    __syncthreads();
    float mu = (s_red[0] + s_red[1] + s_red[2] + s_red[3]) * (1.0f / H);
    __syncthreads();
    float dv = ctx - mu;
    float s2 = dv * dv;
    for (int off = 32; off; off >>= 1) s2 += __shfl_down(s2, off);
    if (lane == 0) s_red[wv] = s2;
    __syncthreads();
    float var = (s_red[0] + s_red[1] + s_red[2] + s_red[3]) * (1.0f / H);
    out[b * H + tid] = dv * rsqrtf(var + 1e-5f) * gamma[tid] + beta[tid];
}

// ---------------- host ----------------
extern "C" void kernel_launch(void* const* d_in, const int* in_sizes, int n_in,
                              void* d_out, int out_size, void* d_ws, size_t ws_size,
                              hipStream_t stream) {
    const float* x     = (const float*)d_in[0];
    const float* Wih0  = (const float*)d_in[1];
    const float* Whh0  = (const float*)d_in[2];
    const float* bih0  = (const float*)d_in[3];
    const float* bhh0  = (const float*)d_in[4];
    const float* Wih1  = (const float*)d_in[5];
    const float* Whh1  = (const float*)d_in[6];
    const float* bih1  = (const float*)d_in[7];
    const float* bhh1  = (const float*)d_in[8];
    const float* aW1   = (const float*)d_in[9];
    const float* aW2   = (const float*)d_in[10];
    const float* aw    = (const float*)d_in[11];
    const float* gamma = (const float*)d_in[12];
    const float* beta  = (const float*)d_in[13];
    float* out = (float*)d_out;

    // ---- workspace layout (bytes), total ~69.5 MB (same as rounds 2/3) ----
    char* base = (char*)d_ws;
    unsigned int* PW   = (unsigned int*)(base);                    // 1,835,008 B
    float* bsum0       = (float*)(base + 1835008);                 // 4096 B
    float* bsum1       = (float*)(base + 1839104);                 // 4096 B
    unsigned int* cnt  = (unsigned int*)(base + 1843200);          // 16,384 B (64 x 256B)
    unsigned int* hxp0 = (unsigned int*)(base + 1859584);          // 65,536 B
    unsigned int* hxp1 = (unsigned int*)(base + 1925120);          // 65,536 B  (ends 1,990,656)
    // attention buffers alias the cnt/hxp region (dead after k_lstm_split)
    float* a2buf       = (float*)(base + 1843200);                 // 65,536 B
    float* scoresb     = (float*)(base + 1908736);                 // 524,288 B (ends 2,433,024)
    unsigned short* lstm2 = (unsigned short*)(base + 2433280);     // 67,108,864 B (B*T*H f16)

    k_zero<<<(B * CNT_STRIDE + 255) / 256, 256, 0, stream>>>(cnt, B * CNT_STRIDE);
    k_pack_w<<<(4 * PQ_UINTS) / 256, 256, 0, stream>>>(Wih0, Whh0, Wih1, Whh1, PW);
    k_bias_sum<<<(G + 255) / 256, 256, 0, stream>>>(bih0, bhh0, bsum0, G);
    k_bias_sum<<<(G + 255) / 256, 256, 0, stream>>>(bih1, bhh1, bsum1, G);

    k_lstm_split<<<256, 1024, 0, stream>>>(x, PW, bsum0, bsum1, hxp0, hxp1, cnt, lstm2);

    k_a2<<<B, H, 0, stream>>>(lstm2, aW2, a2buf);
    k_scores<<<dim3(T / 32, B), 256, 0, stream>>>(lstm2, aW1, a2buf, aw, scoresb);
    k_finish<<<B, 256, 0, stream>>>(lstm2, scoresb, gamma, beta, out);
}

// Round 5
// 10047.569 us; speedup vs baseline: 15.0060x; 1.9107x over previous
//
#include <hip/hip_runtime.h>
#include <hip/hip_bf16.h>
#include <math.h>

#define B 64
#define T 2048
#define D 128
#define H 256
#define G 1024          // 4*H gate rows

// per-q packed weight sizes (in uint = f16-pairs)
#define L0_UINTS 49152   // 192 kpairs * 256 cols
#define L1_UINTS 65536   // 256 kpairs * 256 cols
#define PQ_UINTS (L0_UINTS + L1_UINTS)   // 114688 per q

#define CNT_STRIDE 64    // uints per batch counter (256 B line padding)

typedef _Float16 h2v __attribute__((ext_vector_type(2)));
typedef float f2v __attribute__((ext_vector_type(2)));

#if defined(__has_builtin)
#if __has_builtin(__builtin_amdgcn_fdot2)
#define HAS_FDOT2 1
#endif
#endif

__device__ __forceinline__ float dot2(unsigned int w, unsigned int h, float acc) {
#ifdef HAS_FDOT2
    return __builtin_amdgcn_fdot2(__builtin_bit_cast(h2v, w), __builtin_bit_cast(h2v, h), acc, false);
#else
    h2v wv = __builtin_bit_cast(h2v, w);
    h2v hv = __builtin_bit_cast(h2v, h);
    acc = fmaf((float)wv.x, (float)hv.x, acc);
    return fmaf((float)wv.y, (float)hv.y, acc);
#endif
}

__device__ __forceinline__ unsigned short f2h(float f) {
    _Float16 h = (_Float16)f;
    return __builtin_bit_cast(unsigned short, h);
}
__device__ __forceinline__ float h2f(unsigned short u) {
    return (float)__builtin_bit_cast(_Float16, u);
}
__device__ __forceinline__ unsigned int packh2(float a, float b) {
    return (unsigned int)f2h(a) | ((unsigned int)f2h(b) << 16);
}
__device__ __forceinline__ float sigm(float x) { return 1.0f / (1.0f + __expf(-x)); }
__device__ __forceinline__ float ftanh(float x) {
    x = fminf(fmaxf(x, -15.0f), 15.0f);
    float e = __expf(2.0f * x);
    return (e - 1.0f) / (e + 1.0f);
}

#define DOT4(w0, hp, a0, a1, a2, a3) \
    a0 = dot2(w0.x, hp, a0); a1 = dot2(w0.y, hp, a1); a2 = dot2(w0.z, hp, a2); a3 = dot2(w0.w, hp, a3);

// ---------------- prep ----------------
__global__ void k_zero(unsigned int* p, int n) {
    int i = blockIdx.x * blockDim.x + threadIdx.x;
    if (i < n) p[i] = 0u;
}

__global__ void k_bias_sum(const float* __restrict__ a, const float* __restrict__ b,
                           float* __restrict__ out, int n) {
    int i = blockIdx.x * blockDim.x + threadIdx.x;
    if (i < n) out[i] = a[i] + b[i];
}

// pack f32 weights -> f16 pairs, per-q column slices, k-major
__global__ void k_pack_w(const float* __restrict__ Wih0, const float* __restrict__ Whh0,
                         const float* __restrict__ Wih1, const float* __restrict__ Whh1,
                         unsigned int* __restrict__ PW) {
    int idx = blockIdx.x * blockDim.x + threadIdx.x;
    if (idx >= 4 * PQ_UINTS) return;
    int q = idx / PQ_UINTS;
    int off = idx % PQ_UINTS;
    float v0, v1;
    if (off < L0_UINTS) {
        int kp = off >> 8, c = off & 255;
        int gate = c >> 6, u = c & 63;
        int r = gate * 256 + q * 64 + u;
        int k = kp * 2;
        if (k < 128) { v0 = Wih0[(size_t)r * 128 + k];       v1 = Wih0[(size_t)r * 128 + k + 1]; }
        else         { v0 = Whh0[(size_t)r * 256 + k - 128]; v1 = Whh0[(size_t)r * 256 + k - 127]; }
    } else {
        int o2 = off - L0_UINTS;
        int kp = o2 >> 8, c = o2 & 255;
        int gate = c >> 6, u = c & 63;
        int r = gate * 256 + q * 64 + u;
        int k = kp * 2;
        if (k < 256) { v0 = Wih1[(size_t)r * 256 + k];       v1 = Wih1[(size_t)r * 256 + k + 1]; }
        else         { v0 = Whh1[(size_t)r * 256 + k - 256]; v1 = Whh1[(size_t)r * 256 + k - 255]; }
    }
    PW[idx] = packh2(v0, v1);
}

// ---------------- split fused 2-layer LSTM ----------------
// grid = 256 WGs: q = bid>>6, b = bid&63; 4 WGs per batch, one fence-free
// exchange per step (relaxed agent-scope atomics; round-4-proven).
// NEW: tid<512 = L0 gemm threads, tid>=512 = L1 gemm threads. Each thread
// holds 16 k-pair uint4s (64 VGPRs) of its weight slice permanently in
// registers; remaining k-pairs (8 for L0, 16 for L1) stream from L2.
// x loads and seqo stores are non-temporal so the L2 keeps weight lines.
__global__ __launch_bounds__(1024) void k_lstm_split(
    const float* __restrict__ x,        // B x T x D (f32)
    const unsigned int* __restrict__ PW,
    const float* __restrict__ bs0,      // G
    const float* __restrict__ bs1,      // G
    unsigned int* __restrict__ hxp0,    // B x 2 x 128 (f16-pair packed h0)
    unsigned int* __restrict__ hxp1,    // B x 2 x 128 (f16-pair packed h1)
    unsigned int* __restrict__ cnt,     // B x CNT_STRIDE
    unsigned short* __restrict__ seqo)  // B x T x H (f16)
{
    __shared__ float s_gacc[8][512];    // 16 KB
    __shared__ float s_g[512];
    __shared__ unsigned int s_k0p[192]; // [x pairs 0..63 | h0 pairs 64..191]
    __shared__ unsigned int s_k1p[256]; // [h0 pairs 0..127 | h1 pairs 128..255]

    const int q   = blockIdx.x >> 6;
    const int b   = blockIdx.x & 63;
    const int tid = threadIdx.x;
    const int half = tid >> 9;          // 0 = L0 gemm, 1 = L1 gemm
    const int t2  = tid & 511;
    const int cg  = t2 & 63;            // 4-col group
    const int kb  = t2 >> 6;            // k-block 0..7

    unsigned int* cnt_b = cnt + (size_t)b * CNT_STRIDE;
    const unsigned int* Wq = PW + (size_t)q * PQ_UINTS;

    // per-thread weight base (k-major, 256 uints per kpair row)
    const unsigned int* wbase =
        half == 0 ? (Wq + (size_t)(kb * 24) * 256 + 4 * cg)
                  : (Wq + L0_UINTS + (size_t)(kb * 32) * 256 + 4 * cg);

    // resident weight registers: kpairs 0..15 of this thread's block
    uint4 wr[16];
    #pragma unroll
    for (int i = 0; i < 16; ++i) wr[i] = *(const uint4*)(wbase + (size_t)i * 256);

    float bi0 = 0.f, bi1 = 0.f, bi2 = 0.f, bi3 = 0.f;
    if (tid < 64) {
        int u = q * 64 + tid;
        bi0 = bs0[u]; bi1 = bs0[256 + u]; bi2 = bs0[512 + u]; bi3 = bs0[768 + u];
    } else if (tid < 128) {
        int u = q * 64 + (tid - 64);
        bi0 = bs1[u]; bi1 = bs1[256 + u]; bi2 = bs1[512 + u]; bi3 = bs1[768 + u];
    }
    float c0 = 0.f, c1 = 0.f;

    // prologue staging: zeros for h0(-1), h1(-2); x(0)
    if (tid < 128) s_k0p[64 + tid] = 0u;
    if (tid >= 128 && tid < 384) s_k1p[tid - 128] = 0u;
    if (tid >= 256 && tid < 320) {
        int i = tid - 256;
        f2v v = __builtin_nontemporal_load((const f2v*)(x + (size_t)b * T * D) + i);
        s_k0p[i] = packh2(v.x, v.y);
    }

    for (int t = 0; ; ++t) {
        __syncthreads();                               // A: staging visible

        // ---- gemm: L0 threads (cols 0..255), L1 threads (cols 256..511) ----
        if (half == 0) {
            if (t < T) {
                const unsigned int* sp = s_k0p + kb * 24;
                float a0 = 0.f, a1 = 0.f, a2 = 0.f, a3 = 0.f;
                #pragma unroll
                for (int i = 0; i < 4; ++i) {          // resident kpairs 0..15
                    uint4 hp = *(const uint4*)(sp + 4 * i);
                    DOT4(wr[4 * i + 0], hp.x, a0, a1, a2, a3);
                    DOT4(wr[4 * i + 1], hp.y, a0, a1, a2, a3);
                    DOT4(wr[4 * i + 2], hp.z, a0, a1, a2, a3);
                    DOT4(wr[4 * i + 3], hp.w, a0, a1, a2, a3);
                }
                #pragma unroll
                for (int c = 0; c < 2; ++c) {          // streamed kpairs 16..23
                    int kp = 16 + 4 * c;
                    uint4 w0 = *(const uint4*)(wbase + (size_t)(kp + 0) * 256);
                    uint4 w1 = *(const uint4*)(wbase + (size_t)(kp + 1) * 256);
                    uint4 w2 = *(const uint4*)(wbase + (size_t)(kp + 2) * 256);
                    uint4 w3 = *(const uint4*)(wbase + (size_t)(kp + 3) * 256);
                    uint4 hp = *(const uint4*)(sp + kp);
                    DOT4(w0, hp.x, a0, a1, a2, a3);
                    DOT4(w1, hp.y, a0, a1, a2, a3);
                    DOT4(w2, hp.z, a0, a1, a2, a3);
                    DOT4(w3, hp.w, a0, a1, a2, a3);
                }
                *(float4*)&s_gacc[kb][4 * cg] = make_float4(a0, a1, a2, a3);
            }
        } else {
            const unsigned int* sp = s_k1p + kb * 32;
            float a0 = 0.f, a1 = 0.f, a2 = 0.f, a3 = 0.f;
            #pragma unroll
            for (int i = 0; i < 4; ++i) {              // resident kpairs 0..15
                uint4 hp = *(const uint4*)(sp + 4 * i);
                DOT4(wr[4 * i + 0], hp.x, a0, a1, a2, a3);
                DOT4(wr[4 * i + 1], hp.y, a0, a1, a2, a3);
                DOT4(wr[4 * i + 2], hp.z, a0, a1, a2, a3);
                DOT4(wr[4 * i + 3], hp.w, a0, a1, a2, a3);
            }
            #pragma unroll
            for (int c = 0; c < 4; ++c) {              // streamed kpairs 16..31
                int kp = 16 + 4 * c;
                uint4 w0 = *(const uint4*)(wbase + (size_t)(kp + 0) * 256);
                uint4 w1 = *(const uint4*)(wbase + (size_t)(kp + 1) * 256);
                uint4 w2 = *(const uint4*)(wbase + (size_t)(kp + 2) * 256);
                uint4 w3 = *(const uint4*)(wbase + (size_t)(kp + 3) * 256);
                uint4 hp = *(const uint4*)(sp + kp);
                DOT4(w0, hp.x, a0, a1, a2, a3);
                DOT4(w1, hp.y, a0, a1, a2, a3);
                DOT4(w2, hp.z, a0, a1, a2, a3);
                DOT4(w3, hp.w, a0, a1, a2, a3);
            }
            *(float4*)&s_gacc[kb][256 + 4 * cg] = make_float4(a0, a1, a2, a3);
        }
        __syncthreads();                               // B

        if (tid < 512) {
            float s = s_gacc[0][tid] + s_gacc[1][tid] + s_gacc[2][tid] + s_gacc[3][tid]
                    + s_gacc[4][tid] + s_gacc[5][tid] + s_gacc[6][tid] + s_gacc[7][tid];
            s_g[tid] = s;
        }
        __syncthreads();                               // C

        // ---- owners: nonlinearity + state update + publish (packed, relaxed) ----
        if (tid < 64) {            // layer-0 unit q*64+tid -> h0(t)
            if (t < T) {
                int u = tid;
                float gi = s_g[u] + bi0;
                float gf = s_g[64 + u] + bi1;
                float gg = s_g[128 + u] + bi2;
                float go = s_g[192 + u] + bi3;
                c0 = sigm(gf) * c0 + sigm(gi) * ftanh(gg);
                float h0v = sigm(go) * ftanh(c0);
                float other = __shfl_xor(h0v, 1);
                if ((u & 1) == 0) {
                    __hip_atomic_store(hxp0 + ((size_t)b * 2 + (t & 1)) * 128 + q * 32 + (u >> 1),
                                       packh2(h0v, other), __ATOMIC_RELAXED, __HIP_MEMORY_SCOPE_AGENT);
                }
            }
        } else if (tid < 128) {    // layer-1 unit -> h1(t-1)
            int u = tid - 64;
            float h1v = 0.0f;
            if (t >= 1) {
                float gi = s_g[256 + u] + bi0;
                float gf = s_g[320 + u] + bi1;
                float gg = s_g[384 + u] + bi2;
                float go = s_g[448 + u] + bi3;
                c1 = sigm(gf) * c1 + sigm(gi) * ftanh(gg);
                h1v = sigm(go) * ftanh(c1);
                __builtin_nontemporal_store(f2h(h1v),
                    seqo + ((size_t)b * T + (t - 1)) * H + q * 64 + u);
            }
            if (t < T) {
                float other = __shfl_xor(h1v, 1);
                if ((u & 1) == 0) {
                    __hip_atomic_store(hxp1 + ((size_t)b * 2 + (t & 1)) * 128 + q * 32 + (u >> 1),
                                       packh2(h1v, other), __ATOMIC_RELAXED, __HIP_MEMORY_SCOPE_AGENT);
                }
            }
        }

        if (t == T) break;                             // uniform exit

        __syncthreads();                               // D1: stores drained (vmcnt0 at barrier)

        if (tid == 0) {
            __hip_atomic_fetch_add(cnt_b, 1u, __ATOMIC_RELAXED, __HIP_MEMORY_SCOPE_AGENT);
            while (__hip_atomic_fetch_add(cnt_b, 0u, __ATOMIC_RELAXED, __HIP_MEMORY_SCOPE_AGENT)
                   < 4u * (unsigned)(t + 1))
                __builtin_amdgcn_s_sleep(1);
        }
        __syncthreads();                               // D2

        // ---- read packed h0(t), h1(t-1) from L3; prefetch x(t+1) ----
        {
            const int buf = t & 1;
            if (tid < 128) {
                unsigned int u0 = __hip_atomic_load(hxp0 + ((size_t)b * 2 + buf) * 128 + tid,
                                                    __ATOMIC_RELAXED, __HIP_MEMORY_SCOPE_AGENT);
                s_k0p[64 + tid] = u0;
                s_k1p[tid]      = u0;
            } else if (tid < 256) {
                int i = tid - 128;
                s_k1p[128 + i] = __hip_atomic_load(hxp1 + ((size_t)b * 2 + buf) * 128 + i,
                                                   __ATOMIC_RELAXED, __HIP_MEMORY_SCOPE_AGENT);
            } else if (tid < 320 && (t + 1) < T) {
                int i = tid - 256;
                f2v v = __builtin_nontemporal_load(
                    (const f2v*)(x + ((size_t)b * T + (t + 1)) * D) + i);
                s_k0p[i] = packh2(v.x, v.y);
            }
        }
    }
}

// ---------------- attention ----------------
__global__ __launch_bounds__(256) void k_a2(const unsigned short* __restrict__ lstm_out,
                                            const float* __restrict__ W2,
                                            float* __restrict__ a2out)
{
    __shared__ float s_hT[H];
    int b = blockIdx.x;
    int k = threadIdx.x;
    s_hT[k] = h2f(lstm_out[((size_t)b * T + (T - 1)) * H + k]);
    __syncthreads();
    float acc = 0.f;
    #pragma unroll 4
    for (int h = 0; h < H; ++h) acc += s_hT[h] * W2[h * H + k];
    a2out[b * H + k] = acc;
}

__global__ __launch_bounds__(256) void k_scores(const unsigned short* __restrict__ lstm_out,
                                                const float* __restrict__ W1,
                                                const float* __restrict__ a2,
                                                const float* __restrict__ attn_w,
                                                float* __restrict__ scores)
{
    const int RPB = 32;
    __shared__ float s_rows[RPB][H];   // 32 KB
    __shared__ float s_part[RPB][4];
    int b   = blockIdx.y;
    int t0  = blockIdx.x * RPB;
    int tid = threadIdx.x;

    const unsigned short* lp = lstm_out + ((size_t)b * T + t0) * H;
    for (int i = tid; i < RPB * H / 4; i += 256) {
        ushort4 v = ((const ushort4*)lp)[i];
        int e = i * 4, r = e >> 8, h0 = e & 255;
        *(float4*)&s_rows[r][h0] = make_float4(h2f(v.x), h2f(v.y), h2f(v.z), h2f(v.w));
    }
    __syncthreads();

    int c = tid;
    float acc[RPB];
    #pragma unroll
    for (int r = 0; r < RPB; ++r) acc[r] = 0.f;
    for (int h = 0; h < H; ++h) {
        float w = W1[h * H + c];
        #pragma unroll
        for (int r = 0; r < RPB; ++r) acc[r] += s_rows[r][h] * w;
    }
    float a2v = a2[b * H + c];
    float wc  = attn_w[c];
    int lane = tid & 63, wv = tid >> 6;
    #pragma unroll
    for (int r = 0; r < RPB; ++r) {
        float v = ftanh(acc[r] + a2v) * wc;
        for (int off = 32; off; off >>= 1) v += __shfl_down(v, off);
        if (lane == 0) s_part[r][wv] = v;
    }
    __syncthreads();
    if (tid < RPB) {
        scores[(size_t)b * T + t0 + tid] =
            s_part[tid][0] + s_part[tid][1] + s_part[tid][2] + s_part[tid][3];
    }
}

__global__ __launch_bounds__(256) void k_finish(const unsigned short* __restrict__ lstm_out,
                                                const float* __restrict__ scores,
                                                const float* __restrict__ gamma,
                                                const float* __restrict__ beta,
                                                float* __restrict__ out)
{
    __shared__ float s_p[T];
    __shared__ float s_red[4];
    const int b = blockIdx.x;
    const int tid = threadIdx.x;
    const int lane = tid & 63, wv = tid >> 6;

    const float* sc = scores + (size_t)b * T;
    float m = -1e30f;
    for (int t = tid; t < T; t += 256) m = fmaxf(m, sc[t]);
    for (int off = 32; off; off >>= 1) m = fmaxf(m, __shfl_down(m, off));
    if (lane == 0) s_red[wv] = m;
    __syncthreads();
    m = fmaxf(fmaxf(s_red[0], s_red[1]), fmaxf(s_red[2], s_red[3]));
    __syncthreads();

    float z = 0.f;
    for (int t = tid; t < T; t += 256) { float e = __expf(sc[t] - m); s_p[t] = e; z += e; }
    for (int off = 32; off; off >>= 1) z += __shfl_down(z, off);
    if (lane == 0) s_red[wv] = z;
    __syncthreads();
    z = s_red[0] + s_red[1] + s_red[2] + s_red[3];
    float rz = 1.0f / z;
    __syncthreads();

    const unsigned short* lp = lstm_out + (size_t)b * T * H + tid;
    float ctx = 0.f;
    for (int t = 0; t < T; ++t) ctx += s_p[t] * h2f(lp[(size_t)t * H]);
    ctx *= rz;

    float s1 = ctx;
    for (int off = 32; off; off >>= 1) s1 += __shfl_down(s1, off);
    if (lane == 0) s_red[wv] = s1;
    __syncthreads();
    float mu = (s_red[0] + s_red[1] + s_red[2] + s_red[3]) * (1.0f / H);
    __syncthreads();
    float dv = ctx - mu;
    float s2 = dv * dv;
    for (int off = 32; off; off >>= 1) s2 += __shfl_down(s2, off);
    if (lane == 0) s_red[wv] = s2;
    __syncthreads();
    float var = (s_red[0] + s_red[1] + s_red[2] + s_red[3]) * (1.0f / H);
    out[b * H + tid] = dv * rsqrtf(var + 1e-5f) * gamma[tid] + beta[tid];
}

// ---------------- host ----------------
extern "C" void kernel_launch(void* const* d_in, const int* in_sizes, int n_in,
                              void* d_out, int out_size, void* d_ws, size_t ws_size,
                              hipStream_t stream) {
    const float* x     = (const float*)d_in[0];
    const float* Wih0  = (const float*)d_in[1];
    const float* Whh0  = (const float*)d_in[2];
    const float* bih0  = (const float*)d_in[3];
    const float* bhh0  = (const float*)d_in[4];
    const float* Wih1  = (const float*)d_in[5];
    const float* Whh1  = (const float*)d_in[6];
    const float* bih1  = (const float*)d_in[7];
    const float* bhh1  = (const float*)d_in[8];
    const float* aW1   = (const float*)d_in[9];
    const float* aW2   = (const float*)d_in[10];
    const float* aw    = (const float*)d_in[11];
    const float* gamma = (const float*)d_in[12];
    const float* beta  = (const float*)d_in[13];
    float* out = (float*)d_out;

    // ---- workspace layout (bytes), total ~69.5 MB ----
    char* base = (char*)d_ws;
    unsigned int* PW   = (unsigned int*)(base);                    // 1,835,008 B
    float* bsum0       = (float*)(base + 1835008);                 // 4096 B
    float* bsum1       = (float*)(base + 1839104);                 // 4096 B
    unsigned int* cnt  = (unsigned int*)(base + 1843200);          // 16,384 B (64 x 256B)
    unsigned int* hxp0 = (unsigned int*)(base + 1859584);          // 65,536 B
    unsigned int* hxp1 = (unsigned int*)(base + 1925120);          // 65,536 B
    // attention buffers alias the cnt/hxp region (dead after k_lstm_split)
    float* a2buf       = (float*)(base + 1843200);                 // 65,536 B
    float* scoresb     = (float*)(base + 1908736);                 // 524,288 B
    unsigned short* lstm2 = (unsigned short*)(base + 2433280);     // 67,108,864 B (B*T*H f16)

    k_zero<<<(B * CNT_STRIDE + 255) / 256, 256, 0, stream>>>(cnt, B * CNT_STRIDE);
    k_pack_w<<<(4 * PQ_UINTS) / 256, 256, 0, stream>>>(Wih0, Whh0, Wih1, Whh1, PW);
    k_bias_sum<<<(G + 255) / 256, 256, 0, stream>>>(bih0, bhh0, bsum0, G);
    k_bias_sum<<<(G + 255) / 256, 256, 0, stream>>>(bih1, bhh1, bsum1, G);

    k_lstm_split<<<256, 1024, 0, stream>>>(x, PW, bsum0, bsum1, hxp0, hxp1, cnt, lstm2);

    k_a2<<<B, H, 0, stream>>>(lstm2, aW2, a2buf);
    k_scores<<<dim3(T / 32, B), 256, 0, stream>>>(lstm2, aW1, a2buf, aw, scoresb);
    k_finish<<<B, 256, 0, stream>>>(lstm2, scoresb, gamma, beta, out);
}

// Round 6
// 8200.274 us; speedup vs baseline: 18.3865x; 1.2253x over previous
//
#include <hip/hip_runtime.h>
#include <hip/hip_bf16.h>
#include <math.h>

#define B 64
#define T 2048
#define D 128
#define H 256
#define G 1024          // 4*H gate rows

// per-q packed weight sizes (in uint = f16-pairs)
#define L0_UINTS 49152   // 192 kpairs * 256 cols
#define L1_UINTS 65536   // 256 kpairs * 256 cols
#define PQ_UINTS (L0_UINTS + L1_UINTS)   // 114688 per q

#define L0_RES 22        // resident kpairs per L0 thread (of 24)
#define L1_RES 20        // resident kpairs per L1 thread (of 32)
#define L0_LDS 2
#define L1_LDS 12

typedef _Float16 h2v __attribute__((ext_vector_type(2)));
typedef float f2v __attribute__((ext_vector_type(2)));
typedef unsigned int u4v __attribute__((ext_vector_type(4)));

#if defined(__has_builtin)
#if __has_builtin(__builtin_amdgcn_fdot2)
#define HAS_FDOT2 1
#endif
#endif

__device__ __forceinline__ float dot2(unsigned int w, unsigned int h, float acc) {
#ifdef HAS_FDOT2
    return __builtin_amdgcn_fdot2(__builtin_bit_cast(h2v, w), __builtin_bit_cast(h2v, h), acc, false);
#else
    h2v wv = __builtin_bit_cast(h2v, w);
    h2v hv = __builtin_bit_cast(h2v, h);
    acc = fmaf((float)wv.x, (float)hv.x, acc);
    return fmaf((float)wv.y, (float)hv.y, acc);
#endif
}

__device__ __forceinline__ unsigned short f2h(float f) {
    _Float16 h = (_Float16)f;
    return __builtin_bit_cast(unsigned short, h);
}
__device__ __forceinline__ float h2f(unsigned short u) {
    return (float)__builtin_bit_cast(_Float16, u);
}
__device__ __forceinline__ unsigned int packh2(float a, float b) {
    return (unsigned int)f2h(a) | ((unsigned int)f2h(b) << 16);
}
__device__ __forceinline__ float sigm(float x) { return 1.0f / (1.0f + __expf(-x)); }
__device__ __forceinline__ float ftanh(float x) {
    x = fminf(fmaxf(x, -15.0f), 15.0f);
    float e = __expf(2.0f * x);
    return (e - 1.0f) / (e + 1.0f);
}

#define DOT4(w0, hp, a0, a1, a2, a3) \
    a0 = dot2(w0.x, hp, a0); a1 = dot2(w0.y, hp, a1); a2 = dot2(w0.z, hp, a2); a3 = dot2(w0.w, hp, a3);

// ---------------- prep ----------------
__global__ void k_zero(unsigned int* p, int n) {
    int i = blockIdx.x * blockDim.x + threadIdx.x;
    if (i < n) p[i] = 0u;
}

__global__ void k_bias_sum(const float* __restrict__ a, const float* __restrict__ b,
                           float* __restrict__ out, int n) {
    int i = blockIdx.x * blockDim.x + threadIdx.x;
    if (i < n) out[i] = a[i] + b[i];
}

// pack f32 weights -> f16 pairs, per-q column slices, k-major
__global__ void k_pack_w(const float* __restrict__ Wih0, const float* __restrict__ Whh0,
                         const float* __restrict__ Wih1, const float* __restrict__ Whh1,
                         unsigned int* __restrict__ PW) {
    int idx = blockIdx.x * blockDim.x + threadIdx.x;
    if (idx >= 4 * PQ_UINTS) return;
    int q = idx / PQ_UINTS;
    int off = idx % PQ_UINTS;
    float v0, v1;
    if (off < L0_UINTS) {
        int kp = off >> 8, c = off & 255;
        int gate = c >> 6, u = c & 63;
        int r = gate * 256 + q * 64 + u;
        int k = kp * 2;
        if (k < 128) { v0 = Wih0[(size_t)r * 128 + k];       v1 = Wih0[(size_t)r * 128 + k + 1]; }
        else         { v0 = Whh0[(size_t)r * 256 + k - 128]; v1 = Whh0[(size_t)r * 256 + k - 127]; }
    } else {
        int o2 = off - L0_UINTS;
        int kp = o2 >> 8, c = o2 & 255;
        int gate = c >> 6, u = c & 63;
        int r = gate * 256 + q * 64 + u;
        int k = kp * 2;
        if (k < 256) { v0 = Wih1[(size_t)r * 256 + k];       v1 = Wih1[(size_t)r * 256 + k + 1]; }
        else         { v0 = Whh1[(size_t)r * 256 + k - 256]; v1 = Whh1[(size_t)r * 256 + k - 255]; }
    }
    PW[idx] = packh2(v0, v1);
}

// ---------------- split fused 2-layer LSTM ----------------
// grid = 256 WGs: q = bid>>6, b = bid&63; 4 WGs per batch.
// Weights fully resident: 88/80 VGPRs per thread + 135 KB LDS, zero L2
// weight stream in steady state. Per-producer flag sync, packed 256B h-slice
// exchange via relaxed agent-scope atomics. seq_out batched 8 steps/store,
// time-tiled [B][T/8][H][8] f16.
__global__ __launch_bounds__(1024, 4) void k_lstm_split(
    const float* __restrict__ x,        // B x T x D (f32)
    const unsigned int* __restrict__ PW,
    const float* __restrict__ bs0,      // G
    const float* __restrict__ bs1,      // G
    unsigned int* __restrict__ hxq,     // 2 x 4 x B x 64 uints (packed h0|h1 slices)
    unsigned int* __restrict__ flags,   // 4 x B x 64 uints (padded flag lines)
    unsigned int* __restrict__ seqo)    // B x T/8 x H x 4 uints
{
    __shared__ float s_gacc[8][512];         // 16 KB
    __shared__ float s_g[512];               // 2 KB
    __shared__ unsigned int s_k0p[192];      // [x pairs | h0 pairs]
    __shared__ unsigned int s_k1p[256];      // [h0 pairs | h1 pairs]
    __shared__ uint4 wl0[L0_LDS][512];       // 16 KB  (L0 kpairs 22..23)
    __shared__ uint4 wl1[L1_LDS][512];       // 96 KB  (L1 kpairs 20..31)

    const int q   = blockIdx.x >> 6;
    const int b   = blockIdx.x & 63;
    const int tid = threadIdx.x;
    const int half = tid >> 9;          // 0 = L0 gemm, 1 = L1 gemm
    const int t2  = tid & 511;
    const int cg  = t2 & 63;            // 4-col group
    const int kb  = t2 >> 6;            // k-block 0..7

    const unsigned int* Wq = PW + (size_t)q * PQ_UINTS;
    const unsigned int* wbase =
        half == 0 ? (Wq + (size_t)(kb * 24) * 256 + 4 * cg)
                  : (Wq + L0_UINTS + (size_t)(kb * 32) * 256 + 4 * cg);

    // resident weight registers
    uint4 wr[L0_RES];
    if (half == 0) {
        #pragma unroll
        for (int i = 0; i < L0_RES; ++i) wr[i] = *(const uint4*)(wbase + (size_t)i * 256);
        #pragma unroll
        for (int c = 0; c < L0_LDS; ++c)
            wl0[c][t2] = *(const uint4*)(wbase + (size_t)(L0_RES + c) * 256);
    } else {
        #pragma unroll
        for (int i = 0; i < L1_RES; ++i) wr[i] = *(const uint4*)(wbase + (size_t)i * 256);
        #pragma unroll
        for (int c = 0; c < L1_LDS; ++c)
            wl1[c][t2] = *(const uint4*)(wbase + (size_t)(L1_RES + c) * 256);
    }

    float bi0 = 0.f, bi1 = 0.f, bi2 = 0.f, bi3 = 0.f;
    if (tid < 64) {
        int u = q * 64 + tid;
        bi0 = bs0[u]; bi1 = bs0[256 + u]; bi2 = bs0[512 + u]; bi3 = bs0[768 + u];
    } else if (tid < 128) {
        int u = q * 64 + (tid - 64);
        bi0 = bs1[u]; bi1 = bs1[256 + u]; bi2 = bs1[512 + u]; bi3 = bs1[768 + u];
    }
    float c0 = 0.f, c1 = 0.f;
    unsigned int hb0 = 0u, hb1 = 0u, hb2 = 0u, hb3 = 0u;   // 8-step h1 f16 batch

    // prologue staging: zeros for h0(-1), h1(-2); x(0)
    if (tid < 128) s_k0p[64 + tid] = 0u;
    if (tid >= 128 && tid < 384) s_k1p[tid - 128] = 0u;
    if (tid >= 384 && tid < 448) {
        int i = tid - 384;
        f2v v = __builtin_nontemporal_load((const f2v*)(x + (size_t)b * T * D) + i);
        s_k0p[i] = packh2(v.x, v.y);
    }

    for (int t = 0; ; ++t) {
        __syncthreads();                               // A: staging + weights visible

        // ---- gemm ----
        if (half == 0) {
            if (t < T) {
                const unsigned int* sp = s_k0p + kb * 24;
                float a0 = 0.f, a1 = 0.f, a2 = 0.f, a3 = 0.f;
                #pragma unroll
                for (int i = 0; i < 5; ++i) {          // resident kpairs 0..19
                    uint4 hp = *(const uint4*)(sp + 4 * i);
                    DOT4(wr[4 * i + 0], hp.x, a0, a1, a2, a3);
                    DOT4(wr[4 * i + 1], hp.y, a0, a1, a2, a3);
                    DOT4(wr[4 * i + 2], hp.z, a0, a1, a2, a3);
                    DOT4(wr[4 * i + 3], hp.w, a0, a1, a2, a3);
                }
                {                                      // kpairs 20..23 (2 reg + 2 LDS)
                    uint4 hp = *(const uint4*)(sp + 20);
                    DOT4(wr[20], hp.x, a0, a1, a2, a3);
                    DOT4(wr[21], hp.y, a0, a1, a2, a3);
                    uint4 wa = wl0[0][t2];
                    DOT4(wa, hp.z, a0, a1, a2, a3);
                    uint4 wb = wl0[1][t2];
                    DOT4(wb, hp.w, a0, a1, a2, a3);
                }
                *(float4*)&s_gacc[kb][4 * cg] = make_float4(a0, a1, a2, a3);
            }
        } else {
            const unsigned int* sp = s_k1p + kb * 32;
            float a0 = 0.f, a1 = 0.f, a2 = 0.f, a3 = 0.f;
            #pragma unroll
            for (int i = 0; i < 5; ++i) {              // resident kpairs 0..19
                uint4 hp = *(const uint4*)(sp + 4 * i);
                DOT4(wr[4 * i + 0], hp.x, a0, a1, a2, a3);
                DOT4(wr[4 * i + 1], hp.y, a0, a1, a2, a3);
                DOT4(wr[4 * i + 2], hp.z, a0, a1, a2, a3);
                DOT4(wr[4 * i + 3], hp.w, a0, a1, a2, a3);
            }
            #pragma unroll
            for (int g = 0; g < 3; ++g) {              // kpairs 20..31 from LDS
                uint4 hp = *(const uint4*)(sp + 20 + 4 * g);
                uint4 w0 = wl1[4 * g + 0][t2];
                DOT4(w0, hp.x, a0, a1, a2, a3);
                uint4 w1 = wl1[4 * g + 1][t2];
                DOT4(w1, hp.y, a0, a1, a2, a3);
                uint4 w2 = wl1[4 * g + 2][t2];
                DOT4(w2, hp.z, a0, a1, a2, a3);
                uint4 w3 = wl1[4 * g + 3][t2];
                DOT4(w3, hp.w, a0, a1, a2, a3);
            }
            *(float4*)&s_gacc[kb][256 + 4 * cg] = make_float4(a0, a1, a2, a3);
        }
        __syncthreads();                               // B

        if (tid < 512) {
            float s = s_gacc[0][tid] + s_gacc[1][tid] + s_gacc[2][tid] + s_gacc[3][tid]
                    + s_gacc[4][tid] + s_gacc[5][tid] + s_gacc[6][tid] + s_gacc[7][tid];
            s_g[tid] = s;
        }
        __syncthreads();                               // C

        // ---- owners ----
        if (tid < 64) {            // layer-0 unit q*64+tid -> h0(t)
            if (t < T) {
                int u = tid;
                float gi = s_g[u] + bi0;
                float gf = s_g[64 + u] + bi1;
                float gg = s_g[128 + u] + bi2;
                float go = s_g[192 + u] + bi3;
                c0 = sigm(gf) * c0 + sigm(gi) * ftanh(gg);
                float h0v = sigm(go) * ftanh(c0);
                float other = __shfl_xor(h0v, 1);
                if ((u & 1) == 0) {
                    __hip_atomic_store(hxq + ((((size_t)(t & 1) * 4 + q) * 64 + b) * 64) + (u >> 1),
                                       packh2(h0v, other), __ATOMIC_RELAXED, __HIP_MEMORY_SCOPE_AGENT);
                }
            }
        } else if (tid < 128) {    // layer-1 unit -> h1(t-1)
            int u = tid - 64;
            float h1v = 0.0f;
            if (t >= 1) {
                float gi = s_g[256 + u] + bi0;
                float gf = s_g[320 + u] + bi1;
                float gg = s_g[384 + u] + bi2;
                float go = s_g[448 + u] + bi3;
                c1 = sigm(gf) * c1 + sigm(gi) * ftanh(gg);
                h1v = sigm(go) * ftanh(c1);
                unsigned int hv = (unsigned int)f2h(h1v);
                int s = (t - 1) & 7;
                switch (s) {                           // uniform scalar branch
                    case 0: hb0 = hv; break;
                    case 1: hb0 |= hv << 16; break;
                    case 2: hb1 = hv; break;
                    case 3: hb1 |= hv << 16; break;
                    case 4: hb2 = hv; break;
                    case 5: hb2 |= hv << 16; break;
                    case 6: hb3 = hv; break;
                    default: hb3 |= hv << 16; break;
                }
                if (s == 7) {
                    size_t idx = ((size_t)b * (T / 8) + ((t - 1) >> 3)) * H + (q * 64 + u);
                    u4v val = {hb0, hb1, hb2, hb3};
                    __builtin_nontemporal_store(val, (u4v*)(seqo + idx * 4));
                }
            }
            if (t < T) {
                float other = __shfl_xor(h1v, 1);
                if ((u & 1) == 0) {
                    __hip_atomic_store(hxq + ((((size_t)(t & 1) * 4 + q) * 64 + b) * 64) + 32 + (u >> 1),
                                       packh2(h1v, other), __ATOMIC_RELAXED, __HIP_MEMORY_SCOPE_AGENT);
                }
            }
        }

        if (t == T) break;                             // uniform exit

        __syncthreads();                               // D1: all stores drained (vmcnt0 at barrier)

        if (tid == 0) {
            __hip_atomic_store(flags + ((size_t)q * 64 + b) * 64, (unsigned)(t + 1),
                               __ATOMIC_RELAXED, __HIP_MEMORY_SCOPE_AGENT);
        }

        // ---- parallel per-producer poll + stage; wave 4 prefetches x ----
        {
            const int wv = tid >> 6, l = tid & 63;
            if (wv < 4) {
                unsigned f = 0;
                const unsigned int* fp = flags + ((size_t)wv * 64 + b) * 64;
                do {
                    if (l == 0) f = __hip_atomic_load(fp, __ATOMIC_RELAXED, __HIP_MEMORY_SCOPE_AGENT);
                    f = __shfl(f, 0);
                    if (f < (unsigned)(t + 1)) __builtin_amdgcn_s_sleep(1);
                } while (f < (unsigned)(t + 1));
                unsigned v = __hip_atomic_load(
                    hxq + ((((size_t)(t & 1) * 4 + wv) * 64 + b) * 64) + l,
                    __ATOMIC_RELAXED, __HIP_MEMORY_SCOPE_AGENT);
                if (l < 32) {
                    s_k0p[64 + wv * 32 + l] = v;
                    s_k1p[wv * 32 + l] = v;
                } else {
                    s_k1p[128 + wv * 32 + (l - 32)] = v;
                }
            } else if (wv == 4) {
                if (t + 1 < T) {
                    f2v v = __builtin_nontemporal_load(
                        (const f2v*)(x + ((size_t)b * T + (t + 1)) * D) + l);
                    s_k0p[l] = packh2(v.x, v.y);
                }
            }
        }
    }
}

// ---------------- attention (seqo layout: [B][T/8][H] x uint4 = 8 f16 per (b,tg,h)) ----------------
__global__ __launch_bounds__(256) void k_a2(const unsigned int* __restrict__ seq,
                                            const float* __restrict__ W2,
                                            float* __restrict__ a2out)
{
    __shared__ float s_hT[H];
    int b = blockIdx.x;
    int k = threadIdx.x;
    // h1(T-1): tg=255, slot 7 -> uint index 3, high half
    unsigned v = seq[(((size_t)b * (T / 8) + 255) * H + k) * 4 + 3];
    s_hT[k] = h2f((unsigned short)(v >> 16));
    __syncthreads();
    float acc = 0.f;
    #pragma unroll 4
    for (int h = 0; h < H; ++h) acc += s_hT[h] * W2[h * H + k];
    a2out[b * H + k] = acc;
}

__global__ __launch_bounds__(256) void k_scores(const unsigned int* __restrict__ seq,
                                                const float* __restrict__ W1,
                                                const float* __restrict__ a2,
                                                const float* __restrict__ attn_w,
                                                float* __restrict__ scores)
{
    const int RPB = 32;
    __shared__ float s_rows[RPB][H];   // 32 KB
    __shared__ float s_part[RPB][4];
    int b   = blockIdx.y;
    int t0  = blockIdx.x * RPB;
    int tid = threadIdx.x;

    // stage 32 rows = 4 t-groups
    for (int it = tid; it < 4 * H; it += 256) {
        int tgi = it >> 8, h = it & 255;
        uint4 v = ((const uint4*)seq)[((size_t)b * (T / 8) + (t0 >> 3) + tgi) * H + h];
        int r0 = tgi * 8;
        s_rows[r0 + 0][h] = h2f((unsigned short)v.x);
        s_rows[r0 + 1][h] = h2f((unsigned short)(v.x >> 16));
        s_rows[r0 + 2][h] = h2f((unsigned short)v.y);
        s_rows[r0 + 3][h] = h2f((unsigned short)(v.y >> 16));
        s_rows[r0 + 4][h] = h2f((unsigned short)v.z);
        s_rows[r0 + 5][h] = h2f((unsigned short)(v.z >> 16));
        s_rows[r0 + 6][h] = h2f((unsigned short)v.w);
        s_rows[r0 + 7][h] = h2f((unsigned short)(v.w >> 16));
    }
    __syncthreads();

    int c = tid;
    float acc[RPB];
    #pragma unroll
    for (int r = 0; r < RPB; ++r) acc[r] = 0.f;
    for (int h = 0; h < H; ++h) {
        float w = W1[h * H + c];
        #pragma unroll
        for (int r = 0; r < RPB; ++r) acc[r] += s_rows[r][h] * w;
    }
    float a2v = a2[b * H + c];
    float wc  = attn_w[c];
    int lane = tid & 63, wv = tid >> 6;
    #pragma unroll
    for (int r = 0; r < RPB; ++r) {
        float v = ftanh(acc[r] + a2v) * wc;
        for (int off = 32; off; off >>= 1) v += __shfl_down(v, off);
        if (lane == 0) s_part[r][wv] = v;
    }
    __syncthreads();
    if (tid < RPB) {
        scores[(size_t)b * T + t0 + tid] =
            s_part[tid][0] + s_part[tid][1] + s_part[tid][2] + s_part[tid][3];
    }
}

__global__ __launch_bounds__(256) void k_finish(const unsigned int* __restrict__ seq,
                                                const float* __restrict__ scores,
                                                const float* __restrict__ gamma,
                                                const float* __restrict__ beta,
                                                float* __restrict__ out)
{
    __shared__ float s_p[T];
    __shared__ float s_red[4];
    const int b = blockIdx.x;
    const int tid = threadIdx.x;
    const int lane = tid & 63, wv = tid >> 6;

    const float* sc = scores + (size_t)b * T;
    float m = -1e30f;
    for (int t = tid; t < T; t += 256) m = fmaxf(m, sc[t]);
    for (int off = 32; off; off >>= 1) m = fmaxf(m, __shfl_down(m, off));
    if (lane == 0) s_red[wv] = m;
    __syncthreads();
    m = fmaxf(fmaxf(s_red[0], s_red[1]), fmaxf(s_red[2], s_red[3]));
    __syncthreads();

    float z = 0.f;
    for (int t = tid; t < T; t += 256) { float e = __expf(sc[t] - m); s_p[t] = e; z += e; }
    for (int off = 32; off; off >>= 1) z += __shfl_down(z, off);
    if (lane == 0) s_red[wv] = z;
    __syncthreads();
    z = s_red[0] + s_red[1] + s_red[2] + s_red[3];
    float rz = 1.0f / z;
    __syncthreads();

    // context: per thread h=tid; 16B contiguous load per 8 timesteps
    const uint4* sq = (const uint4*)seq + (size_t)b * (T / 8) * H + tid;
    float ctx = 0.f;
    for (int tg = 0; tg < T / 8; ++tg) {
        uint4 v = sq[(size_t)tg * H];
        const float* pp = &s_p[tg * 8];
        ctx += pp[0] * h2f((unsigned short)v.x) + pp[1] * h2f((unsigned short)(v.x >> 16))
             + pp[2] * h2f((unsigned short)v.y) + pp[3] * h2f((unsigned short)(v.y >> 16))
             + pp[4] * h2f((unsigned short)v.z) + pp[5] * h2f((unsigned short)(v.z >> 16))
             + pp[6] * h2f((unsigned short)v.w) + pp[7] * h2f((unsigned short)(v.w >> 16));
    }
    ctx *= rz;

    float s1 = ctx;
    for (int off = 32; off; off >>= 1) s1 += __shfl_down(s1, off);
    if (lane == 0) s_red[wv] = s1;
    __syncthreads();
    float mu = (s_red[0] + s_red[1] + s_red[2] + s_red[3]) * (1.0f / H);
    __syncthreads();
    float dv = ctx - mu;
    float s2 = dv * dv;
    for (int off = 32; off; off >>= 1) s2 += __shfl_down(s2, off);
    if (lane == 0) s_red[wv] = s2;
    __syncthreads();
    float var = (s_red[0] + s_red[1] + s_red[2] + s_red[3]) * (1.0f / H);
    out[b * H + tid] = dv * rsqrtf(var + 1e-5f) * gamma[tid] + beta[tid];
}

// ---------------- host ----------------
extern "C" void kernel_launch(void* const* d_in, const int* in_sizes, int n_in,
                              void* d_out, int out_size, void* d_ws, size_t ws_size,
                              hipStream_t stream) {
    const float* x     = (const float*)d_in[0];
    const float* Wih0  = (const float*)d_in[1];
    const float* Whh0  = (const float*)d_in[2];
    const float* bih0  = (const float*)d_in[3];
    const float* bhh0  = (const float*)d_in[4];
    const float* Wih1  = (const float*)d_in[5];
    const float* Whh1  = (const float*)d_in[6];
    const float* bih1  = (const float*)d_in[7];
    const float* bhh1  = (const float*)d_in[8];
    const float* aW1   = (const float*)d_in[9];
    const float* aW2   = (const float*)d_in[10];
    const float* aw    = (const float*)d_in[11];
    const float* gamma = (const float*)d_in[12];
    const float* beta  = (const float*)d_in[13];
    float* out = (float*)d_out;

    // ---- workspace layout (bytes), total ~66.5 MB ----
    char* base = (char*)d_ws;
    unsigned int* PW    = (unsigned int*)(base);            // 1,835,008 B
    float* bsum0        = (float*)(base + 1835008);         // 4096 B
    float* bsum1        = (float*)(base + 1839104);         // 4096 B
    unsigned int* flags = (unsigned int*)(base + 1843200);  // 65,536 B  (4x64 padded lines)
    unsigned int* hxq   = (unsigned int*)(base + 1908736);  // 131,072 B (2x4x64x64 uints)
    float* a2buf        = (float*)(base + 2039808);         // 65,536 B
    float* scoresb      = (float*)(base + 2105344);         // 524,288 B
    unsigned int* seqo  = (unsigned int*)(base + 2629632);  // 67,108,864 B (B x T/8 x H x uint4)

    k_zero<<<(4 * 64 * 64 + 255) / 256, 256, 0, stream>>>(flags, 4 * 64 * 64);
    k_pack_w<<<(4 * PQ_UINTS) / 256, 256, 0, stream>>>(Wih0, Whh0, Wih1, Whh1, PW);
    k_bias_sum<<<(G + 255) / 256, 256, 0, stream>>>(bih0, bhh0, bsum0, G);
    k_bias_sum<<<(G + 255) / 256, 256, 0, stream>>>(bih1, bhh1, bsum1, G);

    k_lstm_split<<<256, 1024, 0, stream>>>(x, PW, bsum0, bsum1, hxq, flags, seqo);

    k_a2<<<B, H, 0, stream>>>(seqo, aW2, a2buf);
    k_scores<<<dim3(T / 32, B), 256, 0, stream>>>(seqo, aW1, a2buf, aw, scoresb);
    k_finish<<<B, 256, 0, stream>>>(seqo, scoresb, gamma, beta, out);
}

// Round 7
// 7840.772 us; speedup vs baseline: 19.2295x; 1.0459x over previous
//
#include <hip/hip_runtime.h>
#include <hip/hip_bf16.h>
#include <math.h>

#define B 64
#define T 2048
#define D 128
#define H 256
#define G 1024          // 4*H gate rows

// per-q packed weight sizes (in uint = f16-pairs)
#define L0_UINTS 49152   // 192 kpairs * 256 cols
#define L1_UINTS 65536   // 256 kpairs * 256 cols
#define PQ_UINTS (L0_UINTS + L1_UINTS)   // 114688 per q

#define L0_RES 22        // resident kpairs per L0 thread (of 24)
#define L1_RES 20        // resident kpairs per L1 thread (of 32)
#define L0_LDS 2
#define L1_LDS 12

typedef _Float16 h2v __attribute__((ext_vector_type(2)));
typedef float f2v __attribute__((ext_vector_type(2)));
typedef unsigned int u4v __attribute__((ext_vector_type(4)));

#if defined(__has_builtin)
#if __has_builtin(__builtin_amdgcn_fdot2)
#define HAS_FDOT2 1
#endif
#endif

__device__ __forceinline__ float dot2(unsigned int w, unsigned int h, float acc) {
#ifdef HAS_FDOT2
    return __builtin_amdgcn_fdot2(__builtin_bit_cast(h2v, w), __builtin_bit_cast(h2v, h), acc, false);
#else
    h2v wv = __builtin_bit_cast(h2v, w);
    h2v hv = __builtin_bit_cast(h2v, h);
    acc = fmaf((float)wv.x, (float)hv.x, acc);
    return fmaf((float)wv.y, (float)hv.y, acc);
#endif
}

__device__ __forceinline__ unsigned short f2h(float f) {
    _Float16 h = (_Float16)f;
    return __builtin_bit_cast(unsigned short, h);
}
__device__ __forceinline__ float h2f(unsigned short u) {
    return (float)__builtin_bit_cast(_Float16, u);
}
__device__ __forceinline__ unsigned int packh2(float a, float b) {
    return (unsigned int)f2h(a) | ((unsigned int)f2h(b) << 16);
}
__device__ __forceinline__ float sigm(float x) { return 1.0f / (1.0f + __expf(-x)); }
__device__ __forceinline__ float ftanh(float x) {
    x = fminf(fmaxf(x, -15.0f), 15.0f);
    float e = __expf(2.0f * x);
    return (e - 1.0f) / (e + 1.0f);
}

// Pin a loaded uint4 into VGPRs: the asm "modifies" the value, so the
// compiler cannot rematerialize the load inside the loop (round-6 post-mortem:
// VGPR_Count=64 proved remat; this forces true residency).
__device__ __forceinline__ void pin(uint4& w) {
    asm volatile("" : "+v"(w.x), "+v"(w.y), "+v"(w.z), "+v"(w.w));
}

#define DOT4(w0, hp, a0, a1, a2, a3) \
    a0 = dot2(w0.x, hp, a0); a1 = dot2(w0.y, hp, a1); a2 = dot2(w0.z, hp, a2); a3 = dot2(w0.w, hp, a3);

// ---------------- prep ----------------
__global__ void k_zero(unsigned int* p, int n) {
    int i = blockIdx.x * blockDim.x + threadIdx.x;
    if (i < n) p[i] = 0u;
}

__global__ void k_bias_sum(const float* __restrict__ a, const float* __restrict__ b,
                           float* __restrict__ out, int n) {
    int i = blockIdx.x * blockDim.x + threadIdx.x;
    if (i < n) out[i] = a[i] + b[i];
}

// pack f32 weights -> f16 pairs, per-q column slices, k-major
__global__ void k_pack_w(const float* __restrict__ Wih0, const float* __restrict__ Whh0,
                         const float* __restrict__ Wih1, const float* __restrict__ Whh1,
                         unsigned int* __restrict__ PW) {
    int idx = blockIdx.x * blockDim.x + threadIdx.x;
    if (idx >= 4 * PQ_UINTS) return;
    int q = idx / PQ_UINTS;
    int off = idx % PQ_UINTS;
    float v0, v1;
    if (off < L0_UINTS) {
        int kp = off >> 8, c = off & 255;
        int gate = c >> 6, u = c & 63;
        int r = gate * 256 + q * 64 + u;
        int k = kp * 2;
        if (k < 128) { v0 = Wih0[(size_t)r * 128 + k];       v1 = Wih0[(size_t)r * 128 + k + 1]; }
        else         { v0 = Whh0[(size_t)r * 256 + k - 128]; v1 = Whh0[(size_t)r * 256 + k - 127]; }
    } else {
        int o2 = off - L0_UINTS;
        int kp = o2 >> 8, c = o2 & 255;
        int gate = c >> 6, u = c & 63;
        int r = gate * 256 + q * 64 + u;
        int k = kp * 2;
        if (k < 256) { v0 = Wih1[(size_t)r * 256 + k];       v1 = Wih1[(size_t)r * 256 + k + 1]; }
        else         { v0 = Whh1[(size_t)r * 256 + k - 256]; v1 = Whh1[(size_t)r * 256 + k - 255]; }
    }
    PW[idx] = packh2(v0, v1);
}

// ---------------- split fused 2-layer LSTM ----------------
// grid = 256 WGs: q = bid>>6, b = bid&63; 4 WGs per batch.
// Weights fully resident: 88/80 pinned VGPRs per thread + 112 KB LDS ->
// zero steady-state L2 weight stream. Per-producer flag sync, packed 256B
// h-slice exchange via relaxed agent-scope atomics. seq_out batched 8
// steps/store, time-tiled [B][T/8][H][8] f16.
__global__ __launch_bounds__(1024, 4) void k_lstm_split(
    const float* __restrict__ x,        // B x T x D (f32)
    const unsigned int* __restrict__ PW,
    const float* __restrict__ bs0,      // G
    const float* __restrict__ bs1,      // G
    unsigned int* __restrict__ hxq,     // 2 x 4 x B x 64 uints (packed h0|h1 slices)
    unsigned int* __restrict__ flags,   // 4 x B x 64 uints (padded flag lines)
    unsigned int* __restrict__ seqo)    // B x T/8 x H x 4 uints
{
    __shared__ float s_gacc[8][512];         // 16 KB
    __shared__ float s_g[512];               // 2 KB
    __shared__ unsigned int s_k0p[192];      // [x pairs | h0 pairs]
    __shared__ unsigned int s_k1p[256];      // [h0 pairs | h1 pairs]
    __shared__ uint4 wl0[L0_LDS][512];       // 16 KB  (L0 kpairs 22..23)
    __shared__ uint4 wl1[L1_LDS][512];       // 96 KB  (L1 kpairs 20..31)

    const int q   = blockIdx.x >> 6;
    const int b   = blockIdx.x & 63;
    const int tid = threadIdx.x;
    const int half = tid >> 9;          // 0 = L0 gemm, 1 = L1 gemm
    const int t2  = tid & 511;
    const int cg  = t2 & 63;            // 4-col group
    const int kb  = t2 >> 6;            // k-block 0..7

    const unsigned int* Wq = PW + (size_t)q * PQ_UINTS;
    const unsigned int* wbase =
        half == 0 ? (Wq + (size_t)(kb * 24) * 256 + 4 * cg)
                  : (Wq + L0_UINTS + (size_t)(kb * 32) * 256 + 4 * cg);

    // resident weight registers (pinned -> cannot be rematerialized)
    uint4 wr[L0_RES];
    if (half == 0) {
        #pragma unroll
        for (int i = 0; i < L0_RES; ++i) {
            wr[i] = *(const uint4*)(wbase + (size_t)i * 256);
            pin(wr[i]);
        }
        #pragma unroll
        for (int c = 0; c < L0_LDS; ++c)
            wl0[c][t2] = *(const uint4*)(wbase + (size_t)(L0_RES + c) * 256);
    } else {
        #pragma unroll
        for (int i = 0; i < L1_RES; ++i) {
            wr[i] = *(const uint4*)(wbase + (size_t)i * 256);
            pin(wr[i]);
        }
        #pragma unroll
        for (int c = 0; c < L1_LDS; ++c)
            wl1[c][t2] = *(const uint4*)(wbase + (size_t)(L1_RES + c) * 256);
    }

    float bi0 = 0.f, bi1 = 0.f, bi2 = 0.f, bi3 = 0.f;
    if (tid < 64) {
        int u = q * 64 + tid;
        bi0 = bs0[u]; bi1 = bs0[256 + u]; bi2 = bs0[512 + u]; bi3 = bs0[768 + u];
    } else if (tid < 128) {
        int u = q * 64 + (tid - 64);
        bi0 = bs1[u]; bi1 = bs1[256 + u]; bi2 = bs1[512 + u]; bi3 = bs1[768 + u];
    }
    float c0 = 0.f, c1 = 0.f;
    unsigned int hb0 = 0u, hb1 = 0u, hb2 = 0u, hb3 = 0u;   // 8-step h1 f16 batch

    // prologue staging: zeros for h0(-1), h1(-2); x(0)
    if (tid < 128) s_k0p[64 + tid] = 0u;
    if (tid >= 128 && tid < 384) s_k1p[tid - 128] = 0u;
    if (tid >= 384 && tid < 448) {
        int i = tid - 384;
        f2v v = __builtin_nontemporal_load((const f2v*)(x + (size_t)b * T * D) + i);
        s_k0p[i] = packh2(v.x, v.y);
    }

    for (int t = 0; ; ++t) {
        __syncthreads();                               // A: staging + weights visible

        // ---- gemm ----
        if (half == 0) {
            if (t < T) {
                const unsigned int* sp = s_k0p + kb * 24;
                float a0 = 0.f, a1 = 0.f, a2 = 0.f, a3 = 0.f;
                #pragma unroll
                for (int i = 0; i < 5; ++i) {          // resident kpairs 0..19
                    uint4 hp = *(const uint4*)(sp + 4 * i);
                    DOT4(wr[4 * i + 0], hp.x, a0, a1, a2, a3);
                    DOT4(wr[4 * i + 1], hp.y, a0, a1, a2, a3);
                    DOT4(wr[4 * i + 2], hp.z, a0, a1, a2, a3);
                    DOT4(wr[4 * i + 3], hp.w, a0, a1, a2, a3);
                }
                {                                      // kpairs 20..23 (2 reg + 2 LDS)
                    uint4 hp = *(const uint4*)(sp + 20);
                    DOT4(wr[20], hp.x, a0, a1, a2, a3);
                    DOT4(wr[21], hp.y, a0, a1, a2, a3);
                    uint4 wa = wl0[0][t2];
                    DOT4(wa, hp.z, a0, a1, a2, a3);
                    uint4 wb = wl0[1][t2];
                    DOT4(wb, hp.w, a0, a1, a2, a3);
                }
                *(float4*)&s_gacc[kb][4 * cg] = make_float4(a0, a1, a2, a3);
            }
        } else {
            const unsigned int* sp = s_k1p + kb * 32;
            float a0 = 0.f, a1 = 0.f, a2 = 0.f, a3 = 0.f;
            #pragma unroll
            for (int i = 0; i < 5; ++i) {              // resident kpairs 0..19
                uint4 hp = *(const uint4*)(sp + 4 * i);
                DOT4(wr[4 * i + 0], hp.x, a0, a1, a2, a3);
                DOT4(wr[4 * i + 1], hp.y, a0, a1, a2, a3);
                DOT4(wr[4 * i + 2], hp.z, a0, a1, a2, a3);
                DOT4(wr[4 * i + 3], hp.w, a0, a1, a2, a3);
            }
            #pragma unroll
            for (int g = 0; g < 3; ++g) {              // kpairs 20..31 from LDS
                uint4 hp = *(const uint4*)(sp + 20 + 4 * g);
                uint4 w0 = wl1[4 * g + 0][t2];
                DOT4(w0, hp.x, a0, a1, a2, a3);
                uint4 w1 = wl1[4 * g + 1][t2];
                DOT4(w1, hp.y, a0, a1, a2, a3);
                uint4 w2 = wl1[4 * g + 2][t2];
                DOT4(w2, hp.z, a0, a1, a2, a3);
                uint4 w3 = wl1[4 * g + 3][t2];
                DOT4(w3, hp.w, a0, a1, a2, a3);
            }
            *(float4*)&s_gacc[kb][256 + 4 * cg] = make_float4(a0, a1, a2, a3);
        }
        __syncthreads();                               // B

        if (tid < 512) {
            float s = s_gacc[0][tid] + s_gacc[1][tid] + s_gacc[2][tid] + s_gacc[3][tid]
                    + s_gacc[4][tid] + s_gacc[5][tid] + s_gacc[6][tid] + s_gacc[7][tid];
            s_g[tid] = s;
        }
        __syncthreads();                               // C

        // ---- owners ----
        if (tid < 64) {            // layer-0 unit q*64+tid -> h0(t)
            if (t < T) {
                int u = tid;
                float gi = s_g[u] + bi0;
                float gf = s_g[64 + u] + bi1;
                float gg = s_g[128 + u] + bi2;
                float go = s_g[192 + u] + bi3;
                c0 = sigm(gf) * c0 + sigm(gi) * ftanh(gg);
                float h0v = sigm(go) * ftanh(c0);
                float other = __shfl_xor(h0v, 1);
                if ((u & 1) == 0) {
                    __hip_atomic_store(hxq + ((((size_t)(t & 1) * 4 + q) * 64 + b) * 64) + (u >> 1),
                                       packh2(h0v, other), __ATOMIC_RELAXED, __HIP_MEMORY_SCOPE_AGENT);
                }
            }
        } else if (tid < 128) {    // layer-1 unit -> h1(t-1)
            int u = tid - 64;
            float h1v = 0.0f;
            if (t >= 1) {
                float gi = s_g[256 + u] + bi0;
                float gf = s_g[320 + u] + bi1;
                float gg = s_g[384 + u] + bi2;
                float go = s_g[448 + u] + bi3;
                c1 = sigm(gf) * c1 + sigm(gi) * ftanh(gg);
                h1v = sigm(go) * ftanh(c1);
                unsigned int hv = (unsigned int)f2h(h1v);
                int s = (t - 1) & 7;
                switch (s) {                           // uniform scalar branch
                    case 0: hb0 = hv; break;
                    case 1: hb0 |= hv << 16; break;
                    case 2: hb1 = hv; break;
                    case 3: hb1 |= hv << 16; break;
                    case 4: hb2 = hv; break;
                    case 5: hb2 |= hv << 16; break;
                    case 6: hb3 = hv; break;
                    default: hb3 |= hv << 16; break;
                }
                if (s == 7) {
                    size_t idx = ((size_t)b * (T / 8) + ((t - 1) >> 3)) * H + (q * 64 + u);
                    u4v val = {hb0, hb1, hb2, hb3};
                    __builtin_nontemporal_store(val, (u4v*)(seqo + idx * 4));
                }
            }
            if (t < T) {
                float other = __shfl_xor(h1v, 1);
                if ((u & 1) == 0) {
                    __hip_atomic_store(hxq + ((((size_t)(t & 1) * 4 + q) * 64 + b) * 64) + 32 + (u >> 1),
                                       packh2(h1v, other), __ATOMIC_RELAXED, __HIP_MEMORY_SCOPE_AGENT);
                }
            }
        }

        if (t == T) break;                             // uniform exit

        __syncthreads();                               // D1: all stores drained (vmcnt0 at barrier)

        if (tid == 0) {
            __hip_atomic_store(flags + ((size_t)q * 64 + b) * 64, (unsigned)(t + 1),
                               __ATOMIC_RELAXED, __HIP_MEMORY_SCOPE_AGENT);
        }

        // ---- parallel per-producer poll + stage; wave 4 prefetches x ----
        {
            const int wv = tid >> 6, l = tid & 63;
            if (wv < 4) {
                unsigned f = 0;
                const unsigned int* fp = flags + ((size_t)wv * 64 + b) * 64;
                do {
                    if (l == 0) f = __hip_atomic_load(fp, __ATOMIC_RELAXED, __HIP_MEMORY_SCOPE_AGENT);
                    f = __shfl(f, 0);
                    if (f < (unsigned)(t + 1)) __builtin_amdgcn_s_sleep(1);
                } while (f < (unsigned)(t + 1));
                unsigned v = __hip_atomic_load(
                    hxq + ((((size_t)(t & 1) * 4 + wv) * 64 + b) * 64) + l,
                    __ATOMIC_RELAXED, __HIP_MEMORY_SCOPE_AGENT);
                if (l < 32) {
                    s_k0p[64 + wv * 32 + l] = v;
                    s_k1p[wv * 32 + l] = v;
                } else {
                    s_k1p[128 + wv * 32 + (l - 32)] = v;
                }
            } else if (wv == 4) {
                if (t + 1 < T) {
                    f2v v = __builtin_nontemporal_load(
                        (const f2v*)(x + ((size_t)b * T + (t + 1)) * D) + l);
                    s_k0p[l] = packh2(v.x, v.y);
                }
            }
        }
    }
}

// ---------------- attention (seqo layout: [B][T/8][H] x uint4 = 8 f16 per (b,tg,h)) ----------------
__global__ __launch_bounds__(256) void k_a2(const unsigned int* __restrict__ seq,
                                            const float* __restrict__ W2,
                                            float* __restrict__ a2out)
{
    __shared__ float s_hT[H];
    int b = blockIdx.x;
    int k = threadIdx.x;
    // h1(T-1): tg=255, slot 7 -> uint index 3, high half
    unsigned v = seq[(((size_t)b * (T / 8) + 255) * H + k) * 4 + 3];
    s_hT[k] = h2f((unsigned short)(v >> 16));
    __syncthreads();
    float acc = 0.f;
    #pragma unroll 4
    for (int h = 0; h < H; ++h) acc += s_hT[h] * W2[h * H + k];
    a2out[b * H + k] = acc;
}

__global__ __launch_bounds__(256) void k_scores(const unsigned int* __restrict__ seq,
                                                const float* __restrict__ W1,
                                                const float* __restrict__ a2,
                                                const float* __restrict__ attn_w,
                                                float* __restrict__ scores)
{
    const int RPB = 32;
    __shared__ float s_rows[RPB][H];   // 32 KB
    __shared__ float s_part[RPB][4];
    int b   = blockIdx.y;
    int t0  = blockIdx.x * RPB;
    int tid = threadIdx.x;

    // stage 32 rows = 4 t-groups
    for (int it = tid; it < 4 * H; it += 256) {
        int tgi = it >> 8, h = it & 255;
        uint4 v = ((const uint4*)seq)[((size_t)b * (T / 8) + (t0 >> 3) + tgi) * H + h];
        int r0 = tgi * 8;
        s_rows[r0 + 0][h] = h2f((unsigned short)v.x);
        s_rows[r0 + 1][h] = h2f((unsigned short)(v.x >> 16));
        s_rows[r0 + 2][h] = h2f((unsigned short)v.y);
        s_rows[r0 + 3][h] = h2f((unsigned short)(v.y >> 16));
        s_rows[r0 + 4][h] = h2f((unsigned short)v.z);
        s_rows[r0 + 5][h] = h2f((unsigned short)(v.z >> 16));
        s_rows[r0 + 6][h] = h2f((unsigned short)v.w);
        s_rows[r0 + 7][h] = h2f((unsigned short)(v.w >> 16));
    }
    __syncthreads();

    int c = tid;
    float acc[RPB];
    #pragma unroll
    for (int r = 0; r < RPB; ++r) acc[r] = 0.f;
    for (int h = 0; h < H; ++h) {
        float w = W1[h * H + c];
        #pragma unroll
        for (int r = 0; r < RPB; ++r) acc[r] += s_rows[r][h] * w;
    }
    float a2v = a2[b * H + c];
    float wc  = attn_w[c];
    int lane = tid & 63, wv = tid >> 6;
    #pragma unroll
    for (int r = 0; r < RPB; ++r) {
        float v = ftanh(acc[r] + a2v) * wc;
        for (int off = 32; off; off >>= 1) v += __shfl_down(v, off);
        if (lane == 0) s_part[r][wv] = v;
    }
    __syncthreads();
    if (tid < RPB) {
        scores[(size_t)b * T + t0 + tid] =
            s_part[tid][0] + s_part[tid][1] + s_part[tid][2] + s_part[tid][3];
    }
}

__global__ __launch_bounds__(256) void k_finish(const unsigned int* __restrict__ seq,
                                                const float* __restrict__ scores,
                                                const float* __restrict__ gamma,
                                                const float* __restrict__ beta,
                                                float* __restrict__ out)
{
    __shared__ float s_p[T];
    __shared__ float s_red[4];
    const int b = blockIdx.x;
    const int tid = threadIdx.x;
    const int lane = tid & 63, wv = tid >> 6;

    const float* sc = scores + (size_t)b * T;
    float m = -1e30f;
    for (int t = tid; t < T; t += 256) m = fmaxf(m, sc[t]);
    for (int off = 32; off; off >>= 1) m = fmaxf(m, __shfl_down(m, off));
    if (lane == 0) s_red[wv] = m;
    __syncthreads();
    m = fmaxf(fmaxf(s_red[0], s_red[1]), fmaxf(s_red[2], s_red[3]));
    __syncthreads();

    float z = 0.f;
    for (int t = tid; t < T; t += 256) { float e = __expf(sc[t] - m); s_p[t] = e; z += e; }
    for (int off = 32; off; off >>= 1) z += __shfl_down(z, off);
    if (lane == 0) s_red[wv] = z;
    __syncthreads();
    z = s_red[0] + s_red[1] + s_red[2] + s_red[3];
    float rz = 1.0f / z;
    __syncthreads();

    // context: per thread h=tid; 16B contiguous load per 8 timesteps
    const uint4* sq = (const uint4*)seq + (size_t)b * (T / 8) * H + tid;
    float ctx = 0.f;
    for (int tg = 0; tg < T / 8; ++tg) {
        uint4 v = sq[(size_t)tg * H];
        const float* pp = &s_p[tg * 8];
        ctx += pp[0] * h2f((unsigned short)v.x) + pp[1] * h2f((unsigned short)(v.x >> 16))
             + pp[2] * h2f((unsigned short)v.y) + pp[3] * h2f((unsigned short)(v.y >> 16))
             + pp[4] * h2f((unsigned short)v.z) + pp[5] * h2f((unsigned short)(v.z >> 16))
             + pp[6] * h2f((unsigned short)v.w) + pp[7] * h2f((unsigned short)(v.w >> 16));
    }
    ctx *= rz;

    float s1 = ctx;
    for (int off = 32; off; off >>= 1) s1 += __shfl_down(s1, off);
    if (lane == 0) s_red[wv] = s1;
    __syncthreads();
    float mu = (s_red[0] + s_red[1] + s_red[2] + s_red[3]) * (1.0f / H);
    __syncthreads();
    float dv = ctx - mu;
    float s2 = dv * dv;
    for (int off = 32; off; off >>= 1) s2 += __shfl_down(s2, off);
    if (lane == 0) s_red[wv] = s2;
    __syncthreads();
    float var = (s_red[0] + s_red[1] + s_red[2] + s_red[3]) * (1.0f / H);
    out[b * H + tid] = dv * rsqrtf(var + 1e-5f) * gamma[tid] + beta[tid];
}

// ---------------- host ----------------
extern "C" void kernel_launch(void* const* d_in, const int* in_sizes, int n_in,
                              void* d_out, int out_size, void* d_ws, size_t ws_size,
                              hipStream_t stream) {
    const float* x     = (const float*)d_in[0];
    const float* Wih0  = (const float*)d_in[1];
    const float* Whh0  = (const float*)d_in[2];
    const float* bih0  = (const float*)d_in[3];
    const float* bhh0  = (const float*)d_in[4];
    const float* Wih1  = (const float*)d_in[5];
    const float* Whh1  = (const float*)d_in[6];
    const float* bih1  = (const float*)d_in[7];
    const float* bhh1  = (const float*)d_in[8];
    const float* aW1   = (const float*)d_in[9];
    const float* aW2   = (const float*)d_in[10];
    const float* aw    = (const float*)d_in[11];
    const float* gamma = (const float*)d_in[12];
    const float* beta  = (const float*)d_in[13];
    float* out = (float*)d_out;

    // ---- workspace layout (bytes), total ~66.5 MB ----
    char* base = (char*)d_ws;
    unsigned int* PW    = (unsigned int*)(base);            // 1,835,008 B
    float* bsum0        = (float*)(base + 1835008);         // 4096 B
    float* bsum1        = (float*)(base + 1839104);         // 4096 B
    unsigned int* flags = (unsigned int*)(base + 1843200);  // 65,536 B  (4x64 padded lines)
    unsigned int* hxq   = (unsigned int*)(base + 1908736);  // 131,072 B (2x4x64x64 uints)
    float* a2buf        = (float*)(base + 2039808);         // 65,536 B
    float* scoresb      = (float*)(base + 2105344);         // 524,288 B
    unsigned int* seqo  = (unsigned int*)(base + 2629632);  // 67,108,864 B (B x T/8 x H x uint4)

    k_zero<<<(4 * 64 * 64 + 255) / 256, 256, 0, stream>>>(flags, 4 * 64 * 64);
    k_pack_w<<<(4 * PQ_UINTS) / 256, 256, 0, stream>>>(Wih0, Whh0, Wih1, Whh1, PW);
    k_bias_sum<<<(G + 255) / 256, 256, 0, stream>>>(bih0, bhh0, bsum0, G);
    k_bias_sum<<<(G + 255) / 256, 256, 0, stream>>>(bih1, bhh1, bsum1, G);

    k_lstm_split<<<256, 1024, 0, stream>>>(x, PW, bsum0, bsum1, hxq, flags, seqo);

    k_a2<<<B, H, 0, stream>>>(seqo, aW2, a2buf);
    k_scores<<<dim3(T / 32, B), 256, 0, stream>>>(seqo, aW1, a2buf, aw, scoresb);
    k_finish<<<B, 256, 0, stream>>>(seqo, scoresb, gamma, beta, out);
}